// Round 1
// 495.836 us; speedup vs baseline: 1.0425x; 1.0425x over previous
//
#include <hip/hip_runtime.h>
#include <hip/hip_bf16.h>
#include <math.h>

#define T_LEN 4096
#define D_DIM 512
#define F_DIM 8192
#define NCHUNK 64
#define CLEN 64

typedef short short8 __attribute__((ext_vector_type(8)));
typedef float f32x4 __attribute__((ext_vector_type(4)));
typedef unsigned short u16;
typedef unsigned int u32;

// ---------------- helpers ----------------
__device__ inline float wave_sum(float v) {
#pragma unroll
  for (int o = 32; o; o >>= 1) v += __shfl_xor(v, o);
  return v;
}

__device__ inline u16 f2bf_bits(float v) {
  __hip_bfloat16 h = __float2bfloat16(v);
  return *(u16*)&h;
}

__device__ inline float bf2f(u16 u) {
  u32 x = ((u32)u) << 16;
  return *(float*)&x;
}

__device__ inline void gl_lds16(const void* g, void* l) {
  __builtin_amdgcn_global_load_lds((const __attribute__((address_space(1))) void*)g,
                                   (__attribute__((address_space(3))) void*)l, 16, 0, 0);
}

// start[] may arrive as 1-byte bools or int32 {0,1}.
__global__ void detect_start(const unsigned char* __restrict__ s8, int* __restrict__ mode) {
  __shared__ int found;
  if (threadIdx.x == 0) found = 0;
  __syncthreads();
  for (int i = threadIdx.x; i < 4096; i += 256)
    if ((i & 3) && s8[i]) found = 1;  // benign race, same value
  __syncthreads();
  if (threadIdx.x == 0) mode[0] = found;  // 1 = byte layout, 0 = int32 layout
}

__device__ inline int read_start(const unsigned char* s8, const int* s32, int mode, int t) {
  return mode ? (int)s8[t] : s32[t];
}

// ---------------- fp32 -> bf16(bits) convert (plain) ----------------
__global__ void f2bf(const float* __restrict__ s, u16* __restrict__ d, int n) {
  int i = blockIdx.x * 256 + threadIdx.x;
  if (i < n) d[i] = f2bf_bits(s[i]);
}

// fused per-layer weight conversion:
//   wcat = concat [Wtr_l; Wc_l] (128 x 512), unswizzled (BK=32 gemm)
//   w0bf: K-permute (f = r*128+2c+b <- b*4096+r*64+c) + granule swizzle by (d&7)
__global__ void k_conv(const float* __restrict__ wtr, const float* __restrict__ wc,
                       u16* __restrict__ wcat, const float* __restrict__ w0,
                       u16* __restrict__ w0bf) {
  int i = blockIdx.x * 256 + threadIdx.x;
  if (i < 128 * D_DIM) {
    float v = (i < 64 * D_DIM) ? wtr[i] : wc[i - 64 * D_DIM];
    wcat[i] = f2bf_bits(v);
  }
  int j = i - 128 * D_DIM;
  if (j >= 0 && j < D_DIM * F_DIM) {
    int d = j >> 13, f = j & 8191;
    int r = f >> 7, rem = f & 127;
    int c = rem >> 1, b = rem & 1;
    float v = w0[(size_t)d * 8192 + b * 4096 + r * 64 + c];
    w0bf[(size_t)d * 8192 + (f ^ ((d & 7) << 3))] = f2bf_bits(v);
  }
}

// ---------------- small MFMA GEMM (64x64 tile, BK=32, sync staging) — trct & W1 ----------------
template <int BM, int BN, int WR, int WC>
__global__ __launch_bounds__(256) void gemm_bt(const u16* __restrict__ A,
                                               const u16* __restrict__ B,
                                               float* __restrict__ C, int M, int N, int K) {
  constexpr int BK = 32;
  constexpr int MT = BM / (WR * 16);
  constexpr int NT = BN / (WC * 16);
  constexpr int AG = BM / 64;
  constexpr int BG = BN / 64;
  __shared__ u16 sA[BM * BK];
  __shared__ u16 sB[BN * BK];
  const int m0 = blockIdx.x * BM;
  const int n0 = blockIdx.y * BN;
  const int tid = threadIdx.x;
  const int wave = tid >> 6;
  const int lane = tid & 63;
  const int wr = wave / WC;
  const int wc = wave % WC;
  const int row_l = tid >> 2;
  const int c8 = (tid & 3) << 3;
  const int frow = lane & 15;
  const int fcol = (lane >> 4) << 3;

  f32x4 acc[MT][NT];
#pragma unroll
  for (int i = 0; i < MT; ++i)
#pragma unroll
    for (int j = 0; j < NT; ++j) acc[i][j] = (f32x4){0.f, 0.f, 0.f, 0.f};

  for (int k0 = 0; k0 < K; k0 += BK) {
#pragma unroll
    for (int j = 0; j < AG; ++j) {
      uint4 v = *(const uint4*)(A + (size_t)(m0 + j * 64 + row_l) * K + (k0 + c8));
      *(uint4*)(sA + (j * 64 + row_l) * BK + c8) = v;
    }
#pragma unroll
    for (int j = 0; j < BG; ++j) {
      uint4 v = *(const uint4*)(B + (size_t)(n0 + j * 64 + row_l) * K + (k0 + c8));
      *(uint4*)(sB + (j * 64 + row_l) * BK + c8) = v;
    }
    __syncthreads();
    short8 af[MT], bfr[NT];
#pragma unroll
    for (int i = 0; i < MT; ++i)
      af[i] = *(const short8*)(sA + (wr * MT * 16 + i * 16 + frow) * BK + fcol);
#pragma unroll
    for (int j = 0; j < NT; ++j)
      bfr[j] = *(const short8*)(sB + (wc * NT * 16 + j * 16 + frow) * BK + fcol);
#pragma unroll
    for (int i = 0; i < MT; ++i)
#pragma unroll
      for (int j = 0; j < NT; ++j)
        acc[i][j] = __builtin_amdgcn_mfma_f32_16x16x32_bf16(af[i], bfr[j], acc[i][j], 0, 0, 0);
    __syncthreads();
  }
#pragma unroll
  for (int i = 0; i < MT; ++i) {
    const int rbase = m0 + wr * MT * 16 + i * 16 + ((lane >> 4) << 2);
#pragma unroll
    for (int j = 0; j < NT; ++j) {
      const int col = n0 + wc * NT * 16 + j * 16 + (lane & 15);
#pragma unroll
      for (int rg = 0; rg < 4; ++rg) C[(size_t)(rbase + rg) * N + col] = acc[i][j][rg];
    }
  }
}

// ---------------- 128x128 MFMA GEMM, BK=64, XOR-swizzled operands, split-K, bf16 partials ----
// (retained for low-workspace fallback paths)
// A, B global layout: row-major with 16B granule g of each row stored at g ^ (row&7).
__global__ __launch_bounds__(256) void gemm128(const u16* __restrict__ A,
                                               const u16* __restrict__ B,
                                               u16* __restrict__ Cp, size_t pstride, int N,
                                               int Ktot) {
  __shared__ u16 sA[128 * 64];
  __shared__ u16 sB[128 * 64];
  const int tid = threadIdx.x;
  const int wave = tid >> 6;
  const int lane = tid & 63;
  const int wr = wave >> 1;
  const int wc = wave & 1;
  const int m0 = blockIdx.x * 128;
  const int n0 = blockIdx.y * 128;
  const int ks = blockIdx.z;
  const int Kper = Ktot / gridDim.z;
  const int kb = ks * Kper;
  const int row_s = tid >> 3;     // 0..31 staging row within 32-row group
  const int g8 = (tid & 7) << 3;  // granule offset (elems)
  const int frow = lane & 15;
  const int quad = lane >> 4;
  const int sw = frow & 7;

  f32x4 acc[4][4];
#pragma unroll
  for (int i = 0; i < 4; ++i)
#pragma unroll
    for (int j = 0; j < 4; ++j) acc[i][j] = (f32x4){0.f, 0.f, 0.f, 0.f};

  for (int k0 = kb; k0 < kb + Kper; k0 += 64) {
#pragma unroll
    for (int j = 0; j < 4; ++j) {
      gl_lds16(A + (size_t)(m0 + j * 32 + row_s) * Ktot + (k0 + g8), sA + j * 2048 + wave * 512);
      gl_lds16(B + (size_t)(n0 + j * 32 + row_s) * Ktot + (k0 + g8), sB + j * 2048 + wave * 512);
    }
    asm volatile("s_waitcnt vmcnt(0)" ::: "memory");
    __syncthreads();
#pragma unroll
    for (int kk = 0; kk < 2; ++kk) {
      const int gA = (((kk << 2) | quad) ^ sw) << 3;  // swizzled elem offset in row
      short8 af[4], bfr[4];
#pragma unroll
      for (int i = 0; i < 4; ++i)
        af[i] = *(const short8*)(sA + (wr * 64 + i * 16 + frow) * 64 + gA);
#pragma unroll
      for (int j = 0; j < 4; ++j)
        bfr[j] = *(const short8*)(sB + (wc * 64 + j * 16 + frow) * 64 + gA);
#pragma unroll
      for (int i = 0; i < 4; ++i)
#pragma unroll
        for (int j = 0; j < 4; ++j)
          acc[i][j] = __builtin_amdgcn_mfma_f32_16x16x32_bf16(af[i], bfr[j], acc[i][j], 0, 0, 0);
    }
    __syncthreads();
  }
#pragma unroll
  for (int i = 0; i < 4; ++i) {
    const int rbase = m0 + wr * 64 + i * 16 + ((lane >> 4) << 2);
#pragma unroll
    for (int j = 0; j < 4; ++j) {
      const int col = n0 + wc * 64 + j * 16 + (lane & 15);
#pragma unroll
      for (int rg = 0; rg < 4; ++rg)
        Cp[(size_t)ks * pstride + (size_t)(rbase + rg) * N + col] = f2bf_bits(acc[i][j][rg]);
    }
  }
}

// ---------------- 256x128 MFMA GEMM, 8-phase counted-vmcnt pipeline (T2+T3+T4+T5) ------------
// Same global layouts and swizzle as gemm128; bit-identical accumulation order (KS=4,
// ascending 32-K MFMA steps per acc element, bf16 partial rounding at C-write).
//
// Geometry: BM=256, BN=128, BK=64, 512 threads = 8 waves (WM=2 x WN=4), wave tile 128x32.
// LDS: double-buffered A[2][256*64] + B[2][128*64] bf16 = 96 KiB (dynamic).
// Phase p (p&3 -> quadrant qr=(p>>1)&1, qc=p&1; p>>2 -> buffer/tile half):
//   {ds_read frags | 2x global_load_lds stage} ; barrier ; lgkmcnt(0) ; 8x MFMA ; barrier
// Stage schedule (2 loads/phase, write-after-read safe; see constraints in comments):
//   p0: A_odd{1,3}  p1: B_odd{0,1}  p3: A_nxt_even{0,2}  p4: A_nxt_even{1,3}
//   p5: B_nxt_even{0,1}  p7: A_nxt_odd{0,2}
// vmcnt(2) checkpoints only at end of p3 / p7 (counted, never 0 except final iteration).
__global__ __launch_bounds__(512, 2) void gemm_8ph(const u16* __restrict__ A,
                                                   const u16* __restrict__ B,
                                                   u16* __restrict__ Cp, size_t pstride, int N,
                                                   int Ktot) {
  extern __shared__ u16 smem[];
  u16* sA = smem;           // [2][256*64]
  u16* sB = smem + 32768;   // [2][128*64]
  const int tid = threadIdx.x;
  const int wave = tid >> 6;
  const int lane = tid & 63;
  const int wr = wave >> 2;  // 0..1 -> 128-row half
  const int wc = wave & 3;   // 0..3 -> 32-col group
  const int m0 = blockIdx.x * 256;
  const int n0 = blockIdx.y * 128;
  const int ks = blockIdx.z;
  const int Kper = Ktot / gridDim.z;
  const int kb = ks * Kper;
  const int NITER = Kper >> 7;  // 128 K per iteration (2 x BK=64 tiles)
  const int r_l = tid >> 3;     // row within 64-row load group
  const int g8 = (tid & 7) << 3;
  const int frow = lane & 15;
  const int quad = lane >> 4;
  const int sw = frow & 7;

  const u16* Abase = A + (size_t)(m0 + r_l) * Ktot + g8;
  const u16* Bbase = B + (size_t)(n0 + r_l) * Ktot + g8;

#define STAGE_A(l, k0, b) \
  gl_lds16(Abase + (size_t)(l) * 64 * Ktot + (k0), sA + (b)*16384 + (l)*4096 + wave * 512)
#define STAGE_B(l, k0, b) \
  gl_lds16(Bbase + (size_t)(l) * 64 * Ktot + (k0), sB + (b)*8192 + (l)*4096 + wave * 512)

  f32x4 acc[8][2];
#pragma unroll
  for (int i = 0; i < 8; ++i) {
    acc[i][0] = (f32x4){0.f, 0.f, 0.f, 0.f};
    acc[i][1] = (f32x4){0.f, 0.f, 0.f, 0.f};
  }

  // Prologue: tile0 fully (A:4, B:2 loads) + tile1 A{0,2}; leave the last 2 in flight.
  STAGE_A(0, kb, 0);
  STAGE_A(1, kb, 0);
  STAGE_A(2, kb, 0);
  STAGE_A(3, kb, 0);
  STAGE_B(0, kb, 0);
  STAGE_B(1, kb, 0);
  STAGE_A(0, kb + 64, 1);
  STAGE_A(2, kb + 64, 1);
  asm volatile("s_waitcnt vmcnt(2)" ::: "memory");
  __builtin_amdgcn_s_barrier();

  short8 af[4][2];   // A frags for current qr-half (reloaded on even phases)
  short8 bfc[2][2];  // B frags for current tile (reloaded at p0/p4)

  for (int I = 0; I < NITER; ++I) {
    const int k0e = kb + (I << 7);  // even tile k-offset
    const bool nl = (I < NITER - 1);
#pragma unroll
    for (int p = 0; p < 8; ++p) {
      const int b = p >> 2;
      const int qr = (p >> 1) & 1;
      const int qc = p & 1;
      // ---- register loads from LDS (cached across phases) ----
      if (qc == 0) {
#pragma unroll
        for (int f = 0; f < 4; ++f)
#pragma unroll
          for (int kk = 0; kk < 2; ++kk)
            af[f][kk] = *(const short8*)(sA + b * 16384 +
                                         (wr * 128 + (qr * 4 + f) * 16 + frow) * 64 +
                                         ((((kk << 2) | quad) ^ sw) << 3));
      }
      if (p == 0 || p == 4) {
#pragma unroll
        for (int fc = 0; fc < 2; ++fc)
#pragma unroll
          for (int kk = 0; kk < 2; ++kk)
            bfc[fc][kk] = *(const short8*)(sB + b * 8192 + (wc * 32 + fc * 16 + frow) * 64 +
                                           ((((kk << 2) | quad) ^ sw) << 3));
      }
      // ---- staging (targets sealed regions only; 2 loads/slot) ----
      if (p == 0) { STAGE_A(1, k0e + 64, 1); STAGE_A(3, k0e + 64, 1); }       // buf1 A-r1 (last read prev p6/p7)
      if (p == 1) { STAGE_B(0, k0e + 64, 1); STAGE_B(1, k0e + 64, 1); }       // buf1 B (last read prev p4)
      if (p == 3 && nl) { STAGE_A(0, k0e + 128, 0); STAGE_A(2, k0e + 128, 0); }  // buf0 A-r0 (last read p0/p1)
      if (p == 4 && nl) { STAGE_A(1, k0e + 128, 0); STAGE_A(3, k0e + 128, 0); }  // buf0 A-r1 (last read p2/p3)
      if (p == 5 && nl) { STAGE_B(0, k0e + 128, 0); STAGE_B(1, k0e + 128, 0); }  // buf0 B (last read p0)
      if (p == 7 && nl) { STAGE_A(0, k0e + 192, 1); STAGE_A(2, k0e + 192, 1); }  // buf1 A-r0 (last read p4/p5)
      // ---- sync + compute ----
      __builtin_amdgcn_s_barrier();
      asm volatile("s_waitcnt lgkmcnt(0)" ::: "memory");
      __builtin_amdgcn_sched_barrier(0);
      __builtin_amdgcn_s_setprio(1);
#pragma unroll
      for (int f = 0; f < 4; ++f)
#pragma unroll
        for (int kk = 0; kk < 2; ++kk)
          acc[qr * 4 + f][qc] =
              __builtin_amdgcn_mfma_f32_16x16x32_bf16(af[f][kk], bfc[qc][kk], acc[qr * 4 + f][qc],
                                                      0, 0, 0);
      __builtin_amdgcn_s_setprio(0);
      // ---- counted vmcnt checkpoints (before trailing barrier) ----
      if (p == 3) {
        if (nl)
          asm volatile("s_waitcnt vmcnt(2)" ::: "memory");
        else
          asm volatile("s_waitcnt vmcnt(0)" ::: "memory");
      }
      if (p == 7 && nl) asm volatile("s_waitcnt vmcnt(2)" ::: "memory");
      __builtin_amdgcn_s_barrier();
    }
  }
#undef STAGE_A
#undef STAGE_B

#pragma unroll
  for (int i = 0; i < 8; ++i) {
    const int rbase = m0 + wr * 128 + i * 16 + (quad << 2);
#pragma unroll
    for (int j = 0; j < 2; ++j) {
      const int col = n0 + wc * 32 + j * 16 + frow;
#pragma unroll
      for (int rg = 0; rg < 4; ++rg)
        Cp[(size_t)ks * pstride + (size_t)(rbase + rg) * N + col] = f2bf_bits(acc[i][j][rg]);
    }
  }
}

// ---------------- p/q prep: pT=|tr| transposed, q=|ct|/(1e-8+Sp*Sq) ----------------
__global__ void prep_pq(const float* __restrict__ trct, float* __restrict__ pT,
                        float* __restrict__ q) {
  int t = blockIdx.x;
  int lane = threadIdx.x;  // 64
  float tr = trct[t * 128 + lane];
  float ct = trct[t * 128 + 64 + lane];
  float ap = fabsf(tr), aq = fabsf(ct);
  float Sp = wave_sum(ap);
  float Sq = wave_sum(aq);
  float denom = 1e-8f + Sp * Sq;
  pT[lane * T_LEN + t] = ap;  // transposed for shuffle-broadcast in scans
  q[t * 64 + lane] = aq / denom;
}

// ---------------- scan phase 1: per-chunk affine summary (A,B) ----------------
__global__ void scan_phase1(const float* __restrict__ pT, const float* __restrict__ q,
                            const unsigned char* __restrict__ st8, const int* __restrict__ st32,
                            const int* __restrict__ modep, const float* __restrict__ a,
                            const float* __restrict__ b, float4* __restrict__ chunkbuf) {
  int chunk = blockIdx.x, r = blockIdx.y, c = threadIdx.x;
  int mode = modep[0];
  int t0 = chunk * CLEN;
  float na = -fabsf(a[r]);
  float rho = __expf(na);
  float bb = b[c];
  float er = rho * __cosf(bb), ei = rho * __sinf(bb);
  float pv = pT[r * T_LEN + t0 + c];             // lane c holds p for step c
  int sv = read_start(st8, st32, mode, t0 + c);  // lane c holds start for step c
  unsigned long long bal = __ballot(sv != 0);
  float Ar, Ai;
  if (bal) {
    Ar = 0.f; Ai = 0.f;
  } else {
    float mag = __expf(64.f * na);
    float ang = 64.f * bb;
    Ar = mag * __cosf(ang);
    Ai = mag * __sinf(ang);
  }
  int L = bal ? (63 - __builtin_clzll(bal)) : 0;  // wave-uniform
  float Br = 0.f, Bi = 0.f;
  const float* qrow = q + (size_t)t0 * 64 + c;
  for (int i = L; i < CLEN; ++i) {
    float pre = __shfl(pv, i) * qrow[i * 64];
    float nBr = er * Br - ei * Bi + pre;
    Bi = er * Bi + ei * Br;
    Br = nBr;
  }
  chunkbuf[((size_t)chunk * 64 + r) * 64 + c] = make_float4(Ar, Ai, Br, Bi);
}

// ---------------- scan phase 2: sequential chunk combine ----------------
__global__ void scan_phase2(const float4* __restrict__ chunkbuf, const float* __restrict__ state,
                            float2* __restrict__ s0buf) {
  int r = blockIdx.x, c = threadIdx.x;
  float Sr = state[r * 64 + c], Si = 0.f;
  for (int k = 0; k < NCHUNK; ++k) {
    s0buf[((size_t)k * 64 + r) * 64 + c] = make_float2(Sr, Si);
    float4 ab = chunkbuf[((size_t)k * 64 + r) * 64 + c];
    float nSr = ab.x * Sr - ab.y * Si + ab.z;
    Si = ab.x * Si + ab.y * Sr + ab.w;
    Sr = nSr;
  }
}

// ---------------- scan phase 3: replay + packed log-polar features (swizzled store) ----
__global__ void scan_phase3(const float* __restrict__ pT, const float* __restrict__ q,
                            const unsigned char* __restrict__ st8, const int* __restrict__ st32,
                            const int* __restrict__ modep, const float* __restrict__ a,
                            const float* __restrict__ b, const float2* __restrict__ s0buf,
                            u32* __restrict__ scaled, int c0) {
  int chunk = c0 + blockIdx.x, r = blockIdx.y, c = threadIdx.x;
  int mode = modep[0];
  int t0 = chunk * CLEN;
  float rho = __expf(-fabsf(a[r]));
  float bb = b[c];
  float er = rho * __cosf(bb), ei = rho * __sinf(bb);
  float pv = pT[r * T_LEN + t0 + c];
  int sv = read_start(st8, st32, mode, t0 + c);
  float2 s0 = s0buf[((size_t)chunk * 64 + r) * 64 + c];
  float Sr = s0.x, Si = s0.y;
  int tl0 = (chunk - c0) * CLEN;
  const float* qrow = q + (size_t)t0 * 64 + c;
  u32* srow = scaled + (size_t)tl0 * 4096;
  const int Ldw = r * 64 + c;
#pragma unroll 4
  for (int i = 0; i < CLEN; ++i) {
    float qt = qrow[i * 64];
    float pt = __shfl(pv, i);
    int st = __shfl(sv, i);
    float pre = pt * qt;
    float cer = st ? 0.f : er;
    float cei = st ? 0.f : ei;
    float nSr = cer * Sr - cei * Si + pre;
    Si = cer * Si + cei * Sr;
    Sr = nSr;
    float m2 = fmaf(Sr, Sr, Si * Si);
    float rsq = rsqrtf(fmaxf(m2, 1e-30f));
    float m = m2 * rsq;
    float sc = __log2f(1.0f + m) * 0.6931471805599453f * rsq;
    u32 pack = ((u32)f2bf_bits(sc * Sr) << 16) | (u32)f2bf_bits(sc * Si);
    srow[(size_t)i * 4096 + (Ldw ^ ((i & 7) << 2))] = pack;
  }
}

// ---------------- LN + LeakyReLU over bf16 split-K partials -> z0bf (unswizzled) ----------------
__global__ void ln_act16(const u16* __restrict__ parts, int KS, size_t pstride,
                         const float* __restrict__ bias, const float* __restrict__ gam,
                         const float* __restrict__ bet, u16* __restrict__ zbf) {
  __shared__ float red[8];
  int t = blockIdx.x, tid = threadIdx.x;
  size_t o = (size_t)t * D_DIM + tid;
  float v0 = bias[tid];
  float v1 = bias[tid + 256];
  for (int ks = 0; ks < KS; ++ks) {
    v0 += bf2f(parts[(size_t)ks * pstride + o]);
    v1 += bf2f(parts[(size_t)ks * pstride + o + 256]);
  }
  float s = wave_sum(v0 + v1);
  if ((tid & 63) == 0) red[tid >> 6] = s;
  __syncthreads();
  float mean = (red[0] + red[1] + red[2] + red[3]) * (1.f / 512.f);
  float d0 = v0 - mean, d1 = v1 - mean;
  float s2 = wave_sum(d0 * d0 + d1 * d1);
  if ((tid & 63) == 0) red[4 + (tid >> 6)] = s2;
  __syncthreads();
  float var = (red[4] + red[5] + red[6] + red[7]) * (1.f / 512.f);
  float rstd = rsqrtf(var + 1e-5f);
  float z0 = d0 * rstd * gam[tid] + bet[tid];
  float z1 = d1 * rstd * gam[tid + 256] + bet[tid + 256];
  z0 = z0 > 0.f ? z0 : 0.01f * z0;
  z1 = z1 > 0.f ? z1 : 0.01f * z1;
  zbf[o] = f2bf_bits(z0);
  zbf[o + 256] = f2bf_bits(z1);
}

// ---------------- LN + LeakyReLU over fp32 y (W1 epilogue) ----------------
__global__ void ln_act32(const float* __restrict__ y, const float* __restrict__ bias,
                         const float* __restrict__ gam, const float* __restrict__ bet,
                         const float* __restrict__ xsrc, float* __restrict__ xdst,
                         u16* __restrict__ xbf_next, float* __restrict__ finout) {
  __shared__ float red[8];
  int t = blockIdx.x, tid = threadIdx.x;
  size_t o = (size_t)t * D_DIM + tid;
  float v0 = y[o] + bias[tid];
  float v1 = y[o + 256] + bias[tid + 256];
  float s = wave_sum(v0 + v1);
  if ((tid & 63) == 0) red[tid >> 6] = s;
  __syncthreads();
  float mean = (red[0] + red[1] + red[2] + red[3]) * (1.f / 512.f);
  float d0 = v0 - mean, d1 = v1 - mean;
  float s2 = wave_sum(d0 * d0 + d1 * d1);
  if ((tid & 63) == 0) red[4 + (tid >> 6)] = s2;
  __syncthreads();
  float var = (red[4] + red[5] + red[6] + red[7]) * (1.f / 512.f);
  float rstd = rsqrtf(var + 1e-5f);
  float z0 = d0 * rstd * gam[tid] + bet[tid];
  float z1 = d1 * rstd * gam[tid + 256] + bet[tid + 256];
  z0 = z0 > 0.f ? z0 : 0.01f * z0;
  z1 = z1 > 0.f ? z1 : 0.01f * z1;
  if (xdst) {
    float x0 = xsrc[o] + z0, x1 = xsrc[o + 256] + z1;
    xdst[o] = x0;
    xdst[o + 256] = x1;
    xbf_next[o] = f2bf_bits(x0);
    xbf_next[o + 256] = f2bf_bits(x1);
  }
  if (finout) {
    finout[o] = z0;
    finout[o + 256] = z1;
  }
}

__global__ void err_signal(float* __restrict__ out, float code) {
  if (threadIdx.x == 0) out[0] = code;
}

// ---------------- host launch ----------------
extern "C" void kernel_launch(void* const* d_in, const int* in_sizes, int n_in, void* d_out,
                              int out_size, void* d_ws, size_t ws_size, hipStream_t stream) {
  const float* x_in = (const float*)d_in[0];
  const float* state = (const float*)d_in[1];
  const unsigned char* start8 = (const unsigned char*)d_in[2];
  const int* start32 = (const int*)d_in[2];
  const float* Wtr = (const float*)d_in[3];
  const float* Wc = (const float*)d_in[4];
  const float* a_in = (const float*)d_in[5];
  const float* b_in = (const float*)d_in[6];
  const float* W0 = (const float*)d_in[7];
  const float* b0 = (const float*)d_in[8];
  const float* g0 = (const float*)d_in[9];
  const float* beta0 = (const float*)d_in[10];
  const float* W1 = (const float*)d_in[11];
  const float* b1 = (const float*)d_in[12];
  const float* g1 = (const float*)d_in[13];
  const float* beta1 = (const float*)d_in[14];
  float* out = (float*)d_out;

  // one-time: allow 96 KiB dynamic LDS for the 8-phase GEMM
  static int attr_state = 0;  // 0 unset, 1 ok, -1 failed
  if (attr_state == 0)
    attr_state = (hipFuncSetAttribute((const void*)gemm_8ph,
                                      hipFuncAttributeMaxDynamicSharedMemorySize,
                                      98304) == hipSuccess)
                     ? 1
                     : -1;
  const bool attr_ok = (attr_state == 1);

  char* w = (char*)d_ws;
  auto alloc = [&](size_t bytes) {
    char* ptr = w;
    w += (bytes + 255) & ~(size_t)255;
    return ptr;
  };
  float* x_ws = (float*)alloc(4ull * T_LEN * D_DIM);            // 8 MB
  u16* xbf = (u16*)alloc(2ull * T_LEN * D_DIM);                 // 4 MB
  u16* wcat = (u16*)alloc(2ull * 128 * D_DIM);                  // 128 KB
  u16* w0bf = (u16*)alloc(2ull * D_DIM * F_DIM);                // 8 MB (per-layer)
  u16* w1bf = (u16*)alloc(2ull * 3 * D_DIM * D_DIM);            // 1.5 MB (all layers)
  float* trct = (float*)alloc(4ull * T_LEN * 128);              // 2 MB
  float* pTbuf = (float*)alloc(4ull * T_LEN * 64);              // 1 MB
  float* qbuf = (float*)alloc(4ull * T_LEN * 64);               // 1 MB
  float4* chunkbuf = (float4*)alloc(16ull * NCHUNK * 64 * 64);  // 4 MB
  float2* s0buf = (float2*)alloc(8ull * NCHUNK * 64 * 64);      // 2 MB
  u16* z0bf = (u16*)alloc(2ull * T_LEN * D_DIM);                // 4 MB
  float* ybuf = (float*)alloc(4ull * T_LEN * D_DIM);            // 8 MB (W1 out)
  int* modep = (int*)alloc(256);
  size_t base1 = (size_t)(w - (char*)d_ws);

  if (n_in != 15) {
    err_signal<<<1, 64, 0, stream>>>(out, 9e6f + 1000.f * n_in);
    return;
  }
  const size_t MB = 1ull << 20;
  const size_t pstride = (size_t)T_LEN * D_DIM;  // elements per partial slab
  int KS, nseg;
  if (ws_size >= base1 + 16 * MB + 64 * MB) { KS = 4; nseg = 1; }
  else if (ws_size >= base1 + 16 * MB + 32 * MB) { KS = 4; nseg = 2; }
  else if (ws_size >= base1 + 8 * MB + 32 * MB) { KS = 2; nseg = 2; }
  else if (ws_size >= base1 + 8 * MB + 16 * MB) { KS = 2; nseg = 4; }
  else if (ws_size >= base1 + 4 * MB + 16 * MB) { KS = 1; nseg = 4; }
  else {
    err_signal<<<1, 64, 0, stream>>>(out, 9e6f);
    return;
  }
  const int seg_rows = T_LEN / nseg;
  const int seg_chunks = NCHUNK / nseg;
  u16* ypart = (u16*)alloc(2ull * KS * pstride);
  u16* scaled = (u16*)alloc(2ull * seg_rows * F_DIM);

  const bool use8 = (nseg == 1) && attr_ok;  // seg_rows==4096 -> grid.x=16

  detect_start<<<1, 256, 0, stream>>>(start8, modep);
  f2bf<<<(T_LEN * D_DIM) / 256, 256, 0, stream>>>(x_in, xbf, T_LEN * D_DIM);
  f2bf<<<(3 * D_DIM * D_DIM) / 256, 256, 0, stream>>>(W1, w1bf, 3 * D_DIM * D_DIM);

  for (int l = 0; l < 3; ++l) {
    const float* Wtr_l = Wtr + (size_t)l * 64 * D_DIM;
    const float* Wc_l = Wc + (size_t)l * 64 * D_DIM;
    const float* a_l = a_in + l * 64;
    const float* b_l = b_in + l * 64;
    const float* W0_l = W0 + (size_t)l * D_DIM * F_DIM;
    const u16* w1bf_l = w1bf + (size_t)l * D_DIM * D_DIM;
    const float* state_l = state + (size_t)l * 64 * 64;
    const float* xsrc = (l == 0) ? x_in : x_ws;

    k_conv<<<(128 * D_DIM + D_DIM * F_DIM) / 256, 256, 0, stream>>>(Wtr_l, Wc_l, wcat, W0_l,
                                                                    w0bf);
    // trct (4096 x 128) = xbf @ wcat^T
    gemm_bt<64, 64, 2, 2><<<dim3(T_LEN / 64, 2), 256, 0, stream>>>(xbf, wcat, trct, T_LEN, 128,
                                                                   D_DIM);
    prep_pq<<<T_LEN, 64, 0, stream>>>(trct, pTbuf, qbuf);
    scan_phase1<<<dim3(NCHUNK, 64), 64, 0, stream>>>(pTbuf, qbuf, start8, start32, modep, a_l,
                                                     b_l, chunkbuf);
    scan_phase2<<<64, 64, 0, stream>>>(chunkbuf, state_l, s0buf);

    for (int h = 0; h < nseg; ++h) {
      scan_phase3<<<dim3(seg_chunks, 64), 64, 0, stream>>>(pTbuf, qbuf, start8, start32, modep,
                                                           a_l, b_l, s0buf, (u32*)scaled,
                                                           h * seg_chunks);
      if (use8)
        gemm_8ph<<<dim3(seg_rows / 256, D_DIM / 128, KS), 512, 98304, stream>>>(
            scaled, w0bf, ypart + (size_t)h * seg_rows * D_DIM, pstride, D_DIM, F_DIM);
      else
        gemm128<<<dim3(seg_rows / 128, D_DIM / 128, KS), 256, 0, stream>>>(
            scaled, w0bf, ypart + (size_t)h * seg_rows * D_DIM, pstride, D_DIM, F_DIM);
    }
    ln_act16<<<T_LEN, 256, 0, stream>>>(ypart, KS, pstride, b0 + l * D_DIM, g0 + l * D_DIM,
                                        beta0 + l * D_DIM, z0bf);
    // y2 = z0 (4096x512) @ W1 (512x512)^T — no split-K, grid 64x8 = 512 blocks
    gemm_bt<64, 64, 2, 2><<<dim3(T_LEN / 64, D_DIM / 64), 256, 0, stream>>>(z0bf, w1bf_l, ybuf,
                                                                            T_LEN, D_DIM, D_DIM);
    ln_act32<<<T_LEN, 256, 0, stream>>>(ybuf, b1 + l * D_DIM, g1 + l * D_DIM, beta1 + l * D_DIM,
                                        (l < 2) ? xsrc : nullptr, (l < 2) ? x_ws : nullptr,
                                        (l < 2) ? xbf : nullptr, (l == 2) ? out : nullptr);
  }
}

// Round 2
// 495.686 us; speedup vs baseline: 1.0428x; 1.0003x over previous
//
#include <hip/hip_runtime.h>
#include <hip/hip_bf16.h>
#include <math.h>

#define T_LEN 4096
#define D_DIM 512
#define F_DIM 8192
#define NCHUNK 64
#define CLEN 64

typedef short short8 __attribute__((ext_vector_type(8)));
typedef float f32x4 __attribute__((ext_vector_type(4)));
typedef unsigned short u16;
typedef unsigned int u32;

// ---------------- helpers ----------------
__device__ inline float wave_sum(float v) {
#pragma unroll
  for (int o = 32; o; o >>= 1) v += __shfl_xor(v, o);
  return v;
}

__device__ inline u16 f2bf_bits(float v) {
  __hip_bfloat16 h = __float2bfloat16(v);
  return *(u16*)&h;
}

__device__ inline float bf2f(u16 u) {
  u32 x = ((u32)u) << 16;
  return *(float*)&x;
}

__device__ inline void gl_lds16(const void* g, void* l) {
  __builtin_amdgcn_global_load_lds((const __attribute__((address_space(1))) void*)g,
                                   (__attribute__((address_space(3))) void*)l, 16, 0, 0);
}

// start[] may arrive as 1-byte bools or int32 {0,1}.
__global__ void detect_start(const unsigned char* __restrict__ s8, int* __restrict__ mode) {
  __shared__ int found;
  if (threadIdx.x == 0) found = 0;
  __syncthreads();
  for (int i = threadIdx.x; i < 4096; i += 256)
    if ((i & 3) && s8[i]) found = 1;  // benign race, same value
  __syncthreads();
  if (threadIdx.x == 0) mode[0] = found;  // 1 = byte layout, 0 = int32 layout
}

__device__ inline int read_start(const unsigned char* s8, const int* s32, int mode, int t) {
  return mode ? (int)s8[t] : s32[t];
}

// ---------------- fp32 -> bf16(bits) convert (plain) ----------------
__global__ void f2bf(const float* __restrict__ s, u16* __restrict__ d, int n) {
  int i = blockIdx.x * 256 + threadIdx.x;
  if (i < n) d[i] = f2bf_bits(s[i]);
}

// fused per-layer weight conversion:
//   wcat = concat [Wtr_l; Wc_l] (128 x 512), unswizzled (BK=32 gemm)
//   w0bf: K-permute (f = r*128+2c+b <- b*4096+r*64+c) + granule swizzle by (d&7)
__global__ void k_conv(const float* __restrict__ wtr, const float* __restrict__ wc,
                       u16* __restrict__ wcat, const float* __restrict__ w0,
                       u16* __restrict__ w0bf) {
  int i = blockIdx.x * 256 + threadIdx.x;
  if (i < 128 * D_DIM) {
    float v = (i < 64 * D_DIM) ? wtr[i] : wc[i - 64 * D_DIM];
    wcat[i] = f2bf_bits(v);
  }
  int j = i - 128 * D_DIM;
  if (j >= 0 && j < D_DIM * F_DIM) {
    int d = j >> 13, f = j & 8191;
    int r = f >> 7, rem = f & 127;
    int c = rem >> 1, b = rem & 1;
    float v = w0[(size_t)d * 8192 + b * 4096 + r * 64 + c];
    w0bf[(size_t)d * 8192 + (f ^ ((d & 7) << 3))] = f2bf_bits(v);
  }
}

// ---------------- small MFMA GEMM (64x64 tile, BK=32, sync staging) — trct & W1 ----------------
template <int BM, int BN, int WR, int WC>
__global__ __launch_bounds__(256) void gemm_bt(const u16* __restrict__ A,
                                               const u16* __restrict__ B,
                                               float* __restrict__ C, int M, int N, int K) {
  constexpr int BK = 32;
  constexpr int MT = BM / (WR * 16);
  constexpr int NT = BN / (WC * 16);
  constexpr int AG = BM / 64;
  constexpr int BG = BN / 64;
  __shared__ u16 sA[BM * BK];
  __shared__ u16 sB[BN * BK];
  const int m0 = blockIdx.x * BM;
  const int n0 = blockIdx.y * BN;
  const int tid = threadIdx.x;
  const int wave = tid >> 6;
  const int lane = tid & 63;
  const int wr = wave / WC;
  const int wc = wave % WC;
  const int row_l = tid >> 2;
  const int c8 = (tid & 3) << 3;
  const int frow = lane & 15;
  const int fcol = (lane >> 4) << 3;

  f32x4 acc[MT][NT];
#pragma unroll
  for (int i = 0; i < MT; ++i)
#pragma unroll
    for (int j = 0; j < NT; ++j) acc[i][j] = (f32x4){0.f, 0.f, 0.f, 0.f};

  for (int k0 = 0; k0 < K; k0 += BK) {
#pragma unroll
    for (int j = 0; j < AG; ++j) {
      uint4 v = *(const uint4*)(A + (size_t)(m0 + j * 64 + row_l) * K + (k0 + c8));
      *(uint4*)(sA + (j * 64 + row_l) * BK + c8) = v;
    }
#pragma unroll
    for (int j = 0; j < BG; ++j) {
      uint4 v = *(const uint4*)(B + (size_t)(n0 + j * 64 + row_l) * K + (k0 + c8));
      *(uint4*)(sB + (j * 64 + row_l) * BK + c8) = v;
    }
    __syncthreads();
    short8 af[MT], bfr[NT];
#pragma unroll
    for (int i = 0; i < MT; ++i)
      af[i] = *(const short8*)(sA + (wr * MT * 16 + i * 16 + frow) * BK + fcol);
#pragma unroll
    for (int j = 0; j < NT; ++j)
      bfr[j] = *(const short8*)(sB + (wc * NT * 16 + j * 16 + frow) * BK + fcol);
#pragma unroll
    for (int i = 0; i < MT; ++i)
#pragma unroll
      for (int j = 0; j < NT; ++j)
        acc[i][j] = __builtin_amdgcn_mfma_f32_16x16x32_bf16(af[i], bfr[j], acc[i][j], 0, 0, 0);
    __syncthreads();
  }
#pragma unroll
  for (int i = 0; i < MT; ++i) {
    const int rbase = m0 + wr * MT * 16 + i * 16 + ((lane >> 4) << 2);
#pragma unroll
    for (int j = 0; j < NT; ++j) {
      const int col = n0 + wc * NT * 16 + j * 16 + (lane & 15);
#pragma unroll
      for (int rg = 0; rg < 4; ++rg) C[(size_t)(rbase + rg) * N + col] = acc[i][j][rg];
    }
  }
}

// ---------------- 128x128 MFMA GEMM, BK=64, XOR-swizzled operands, split-K, bf16 partials ----
// (retained for low-workspace fallback paths)
// A, B global layout: row-major with 16B granule g of each row stored at g ^ (row&7).
__global__ __launch_bounds__(256) void gemm128(const u16* __restrict__ A,
                                               const u16* __restrict__ B,
                                               u16* __restrict__ Cp, size_t pstride, int N,
                                               int Ktot) {
  __shared__ u16 sA[128 * 64];
  __shared__ u16 sB[128 * 64];
  const int tid = threadIdx.x;
  const int wave = tid >> 6;
  const int lane = tid & 63;
  const int wr = wave >> 1;
  const int wc = wave & 1;
  const int m0 = blockIdx.x * 128;
  const int n0 = blockIdx.y * 128;
  const int ks = blockIdx.z;
  const int Kper = Ktot / gridDim.z;
  const int kb = ks * Kper;
  const int row_s = tid >> 3;     // 0..31 staging row within 32-row group
  const int g8 = (tid & 7) << 3;  // granule offset (elems)
  const int frow = lane & 15;
  const int quad = lane >> 4;
  const int sw = frow & 7;

  f32x4 acc[4][4];
#pragma unroll
  for (int i = 0; i < 4; ++i)
#pragma unroll
    for (int j = 0; j < 4; ++j) acc[i][j] = (f32x4){0.f, 0.f, 0.f, 0.f};

  for (int k0 = kb; k0 < kb + Kper; k0 += 64) {
#pragma unroll
    for (int j = 0; j < 4; ++j) {
      gl_lds16(A + (size_t)(m0 + j * 32 + row_s) * Ktot + (k0 + g8), sA + j * 2048 + wave * 512);
      gl_lds16(B + (size_t)(n0 + j * 32 + row_s) * Ktot + (k0 + g8), sB + j * 2048 + wave * 512);
    }
    asm volatile("s_waitcnt vmcnt(0)" ::: "memory");
    __syncthreads();
#pragma unroll
    for (int kk = 0; kk < 2; ++kk) {
      const int gA = (((kk << 2) | quad) ^ sw) << 3;  // swizzled elem offset in row
      short8 af[4], bfr[4];
#pragma unroll
      for (int i = 0; i < 4; ++i)
        af[i] = *(const short8*)(sA + (wr * 64 + i * 16 + frow) * 64 + gA);
#pragma unroll
      for (int j = 0; j < 4; ++j)
        bfr[j] = *(const short8*)(sB + (wc * 64 + j * 16 + frow) * 64 + gA);
#pragma unroll
      for (int i = 0; i < 4; ++i)
#pragma unroll
        for (int j = 0; j < 4; ++j)
          acc[i][j] = __builtin_amdgcn_mfma_f32_16x16x32_bf16(af[i], bfr[j], acc[i][j], 0, 0, 0);
    }
    __syncthreads();
  }
#pragma unroll
  for (int i = 0; i < 4; ++i) {
    const int rbase = m0 + wr * 64 + i * 16 + ((lane >> 4) << 2);
#pragma unroll
    for (int j = 0; j < 4; ++j) {
      const int col = n0 + wc * 64 + j * 16 + (lane & 15);
#pragma unroll
      for (int rg = 0; rg < 4; ++rg)
        Cp[(size_t)ks * pstride + (size_t)(rbase + rg) * N + col] = f2bf_bits(acc[i][j][rg]);
    }
  }
}

// ---------------- 256x128 MFMA GEMM, 8-phase counted-vmcnt pipeline (T2+T3+T4+T5) ------------
// v2: wave tile 64x64 (8 waves = 4M x 2N). Per-wave LDS fragment traffic is
// (WM+WN)*BK*2B per K-tile; 64x64 gives 16KB/wave/tile vs 128x32's 20KB for the same
// FLOP -> LDS-read/MFMA cycle ratio drops 1.03 -> 0.83 (LDS-BW was the R1 limiter).
// Same global layouts/swizzle as gemm128; bit-identical accumulation order (KS=4,
// ascending 32-K MFMA steps per acc element, bf16 partial rounding at C-write).
//
// Geometry: BM=256, BN=128, BK=64, 512 threads = 8 waves (wr=wave>>1: 64-row group,
// wc=wave&1: 64-col group). LDS: double-buffered A[2][256*64] + B[2][128*64] = 96 KiB.
// Per K-tile: 4 phases, gray-coded C-quadrants (qm,qn): 00 -> 01 -> 11 -> 10, so
// bf0 (n-frags 0,1; loaded q0) is reused at q3 and afr reloads once (q0: m0,1 / q2: m2,3).
// Each LDS element is read exactly once per wave per tile.
// Stage schedule (unchanged from v1; write-after-read re-verified for the new reads:
// A{1,3} last read prev-p6 < p0-stage; A{0,2} at p2 < p3-stage; B at p1 < p5-stage):
//   p0: A_odd{1,3}  p1: B_odd{0,1}  p3: A_nxt_even{0,2}  p4: A_nxt_even{1,3}
//   p5: B_nxt_even{0,1}  p7: A_nxt_odd{0,2}
// vmcnt(2) checkpoints only at end of p3 / p7 (counted, never 0 except final iteration).
__global__ __launch_bounds__(512, 2) void gemm_8ph(const u16* __restrict__ A,
                                                   const u16* __restrict__ B,
                                                   u16* __restrict__ Cp, size_t pstride, int N,
                                                   int Ktot) {
  extern __shared__ u16 smem[];
  u16* sA = smem;          // [2][256*64]
  u16* sB = smem + 32768;  // [2][128*64]
  const int tid = threadIdx.x;
  const int wave = tid >> 6;
  const int lane = tid & 63;
  const int wr = wave >> 1;  // 0..3 -> 64-row group
  const int wc = wave & 1;   // 0..1 -> 64-col group
  const int m0 = blockIdx.x * 256;
  const int n0 = blockIdx.y * 128;
  const int ks = blockIdx.z;
  const int Kper = Ktot / gridDim.z;
  const int kb = ks * Kper;
  const int NITER = Kper >> 7;  // 128 K per iteration (2 x BK=64 tiles)
  const int r_l = tid >> 3;     // row within 64-row load group
  const int g8 = (tid & 7) << 3;
  const int frow = lane & 15;
  const int quad = lane >> 4;
  const int sw = frow & 7;

  const u16* Abase = A + (size_t)(m0 + r_l) * Ktot + g8;
  const u16* Bbase = B + (size_t)(n0 + r_l) * Ktot + g8;

#define STAGE_A(l, k0, b) \
  gl_lds16(Abase + (size_t)(l) * 64 * Ktot + (k0), sA + (b)*16384 + (l)*4096 + wave * 512)
#define STAGE_B(l, k0, b) \
  gl_lds16(Bbase + (size_t)(l) * 64 * Ktot + (k0), sB + (b)*8192 + (l)*4096 + wave * 512)

  f32x4 acc[4][4];
#pragma unroll
  for (int i = 0; i < 4; ++i)
#pragma unroll
    for (int j = 0; j < 4; ++j) acc[i][j] = (f32x4){0.f, 0.f, 0.f, 0.f};

  // Prologue: tile0 fully (A:4, B:2 loads) + tile1 A{0,2}; leave the last 2 in flight.
  STAGE_A(0, kb, 0);
  STAGE_A(1, kb, 0);
  STAGE_A(2, kb, 0);
  STAGE_A(3, kb, 0);
  STAGE_B(0, kb, 0);
  STAGE_B(1, kb, 0);
  STAGE_A(0, kb + 64, 1);
  STAGE_A(2, kb + 64, 1);
  asm volatile("s_waitcnt vmcnt(2)" ::: "memory");
  __builtin_amdgcn_s_barrier();

  short8 afr[2][2];  // A frags for current qm-half (reloaded at q0/q2)
  short8 bf0[2][2];  // B frags n=0,1 (loaded at q0, reused at q3)
  short8 bf1[2][2];  // B frags n=2,3 (loaded at q1, reused at q2)

  for (int I = 0; I < NITER; ++I) {
    const int k0e = kb + (I << 7);  // even tile k-offset
    const bool nl = (I < NITER - 1);
#pragma unroll
    for (int p = 0; p < 8; ++p) {
      const int b = p >> 2;
      const int q = p & 3;
      const int qm = q >> 1;
      const int qn = qm ^ (q & 1);  // gray code: 00,01,11,10
      // ---- register loads from LDS (each element read once per tile) ----
      if (q == 0 || q == 2) {
#pragma unroll
        for (int f = 0; f < 2; ++f)
#pragma unroll
          for (int kk = 0; kk < 2; ++kk)
            afr[f][kk] = *(const short8*)(sA + b * 16384 +
                                          (wr * 64 + (qm * 2 + f) * 16 + frow) * 64 +
                                          ((((kk << 2) | quad) ^ sw) << 3));
      }
      if (q == 0) {
#pragma unroll
        for (int g = 0; g < 2; ++g)
#pragma unroll
          for (int kk = 0; kk < 2; ++kk)
            bf0[g][kk] = *(const short8*)(sB + b * 8192 + (wc * 64 + g * 16 + frow) * 64 +
                                          ((((kk << 2) | quad) ^ sw) << 3));
      }
      if (q == 1) {
#pragma unroll
        for (int g = 0; g < 2; ++g)
#pragma unroll
          for (int kk = 0; kk < 2; ++kk)
            bf1[g][kk] = *(const short8*)(sB + b * 8192 + (wc * 64 + 32 + g * 16 + frow) * 64 +
                                          ((((kk << 2) | quad) ^ sw) << 3));
      }
      // ---- staging (targets sealed regions only; 2 loads/slot) ----
      if (p == 0) { STAGE_A(1, k0e + 64, 1); STAGE_A(3, k0e + 64, 1); }
      if (p == 1) { STAGE_B(0, k0e + 64, 1); STAGE_B(1, k0e + 64, 1); }
      if (p == 3 && nl) { STAGE_A(0, k0e + 128, 0); STAGE_A(2, k0e + 128, 0); }
      if (p == 4 && nl) { STAGE_A(1, k0e + 128, 0); STAGE_A(3, k0e + 128, 0); }
      if (p == 5 && nl) { STAGE_B(0, k0e + 128, 0); STAGE_B(1, k0e + 128, 0); }
      if (p == 7 && nl) { STAGE_A(0, k0e + 192, 1); STAGE_A(2, k0e + 192, 1); }
      // ---- sync + compute ----
      __builtin_amdgcn_s_barrier();
      asm volatile("s_waitcnt lgkmcnt(0)" ::: "memory");
      __builtin_amdgcn_sched_barrier(0);
      __builtin_amdgcn_s_setprio(1);
      if (qn == 0) {
#pragma unroll
        for (int f = 0; f < 2; ++f)
#pragma unroll
          for (int g = 0; g < 2; ++g)
#pragma unroll
            for (int kk = 0; kk < 2; ++kk)
              acc[qm * 2 + f][g] = __builtin_amdgcn_mfma_f32_16x16x32_bf16(
                  afr[f][kk], bf0[g][kk], acc[qm * 2 + f][g], 0, 0, 0);
      } else {
#pragma unroll
        for (int f = 0; f < 2; ++f)
#pragma unroll
          for (int g = 0; g < 2; ++g)
#pragma unroll
            for (int kk = 0; kk < 2; ++kk)
              acc[qm * 2 + f][2 + g] = __builtin_amdgcn_mfma_f32_16x16x32_bf16(
                  afr[f][kk], bf1[g][kk], acc[qm * 2 + f][2 + g], 0, 0, 0);
      }
      __builtin_amdgcn_s_setprio(0);
      // ---- counted vmcnt checkpoints (before trailing barrier) ----
      if (p == 3) {
        if (nl)
          asm volatile("s_waitcnt vmcnt(2)" ::: "memory");
        else
          asm volatile("s_waitcnt vmcnt(0)" ::: "memory");
      }
      if (p == 7 && nl) asm volatile("s_waitcnt vmcnt(2)" ::: "memory");
      __builtin_amdgcn_s_barrier();
    }
  }
#undef STAGE_A
#undef STAGE_B

#pragma unroll
  for (int i = 0; i < 4; ++i) {
    const int rbase = m0 + wr * 64 + i * 16 + (quad << 2);
#pragma unroll
    for (int j = 0; j < 4; ++j) {
      const int col = n0 + wc * 64 + j * 16 + frow;
#pragma unroll
      for (int rg = 0; rg < 4; ++rg)
        Cp[(size_t)ks * pstride + (size_t)(rbase + rg) * N + col] = f2bf_bits(acc[i][j][rg]);
    }
  }
}

// ---------------- p/q prep: pT=|tr| transposed, q=|ct|/(1e-8+Sp*Sq) ----------------
__global__ void prep_pq(const float* __restrict__ trct, float* __restrict__ pT,
                        float* __restrict__ q) {
  int t = blockIdx.x;
  int lane = threadIdx.x;  // 64
  float tr = trct[t * 128 + lane];
  float ct = trct[t * 128 + 64 + lane];
  float ap = fabsf(tr), aq = fabsf(ct);
  float Sp = wave_sum(ap);
  float Sq = wave_sum(aq);
  float denom = 1e-8f + Sp * Sq;
  pT[lane * T_LEN + t] = ap;  // transposed for shuffle-broadcast in scans
  q[t * 64 + lane] = aq / denom;
}

// ---------------- scan phase 1: per-chunk affine summary (A,B) ----------------
__global__ void scan_phase1(const float* __restrict__ pT, const float* __restrict__ q,
                            const unsigned char* __restrict__ st8, const int* __restrict__ st32,
                            const int* __restrict__ modep, const float* __restrict__ a,
                            const float* __restrict__ b, float4* __restrict__ chunkbuf) {
  int chunk = blockIdx.x, r = blockIdx.y, c = threadIdx.x;
  int mode = modep[0];
  int t0 = chunk * CLEN;
  float na = -fabsf(a[r]);
  float rho = __expf(na);
  float bb = b[c];
  float er = rho * __cosf(bb), ei = rho * __sinf(bb);
  float pv = pT[r * T_LEN + t0 + c];             // lane c holds p for step c
  int sv = read_start(st8, st32, mode, t0 + c);  // lane c holds start for step c
  unsigned long long bal = __ballot(sv != 0);
  float Ar, Ai;
  if (bal) {
    Ar = 0.f; Ai = 0.f;
  } else {
    float mag = __expf(64.f * na);
    float ang = 64.f * bb;
    Ar = mag * __cosf(ang);
    Ai = mag * __sinf(ang);
  }
  int L = bal ? (63 - __builtin_clzll(bal)) : 0;  // wave-uniform
  float Br = 0.f, Bi = 0.f;
  const float* qrow = q + (size_t)t0 * 64 + c;
  for (int i = L; i < CLEN; ++i) {
    float pre = __shfl(pv, i) * qrow[i * 64];
    float nBr = er * Br - ei * Bi + pre;
    Bi = er * Bi + ei * Br;
    Br = nBr;
  }
  chunkbuf[((size_t)chunk * 64 + r) * 64 + c] = make_float4(Ar, Ai, Br, Bi);
}

// ---------------- scan phase 2: sequential chunk combine ----------------
__global__ void scan_phase2(const float4* __restrict__ chunkbuf, const float* __restrict__ state,
                            float2* __restrict__ s0buf) {
  int r = blockIdx.x, c = threadIdx.x;
  float Sr = state[r * 64 + c], Si = 0.f;
  for (int k = 0; k < NCHUNK; ++k) {
    s0buf[((size_t)k * 64 + r) * 64 + c] = make_float2(Sr, Si);
    float4 ab = chunkbuf[((size_t)k * 64 + r) * 64 + c];
    float nSr = ab.x * Sr - ab.y * Si + ab.z;
    Si = ab.x * Si + ab.y * Sr + ab.w;
    Sr = nSr;
  }
}

// ---------------- scan phase 3: replay + packed log-polar features (swizzled store) ----
__global__ void scan_phase3(const float* __restrict__ pT, const float* __restrict__ q,
                            const unsigned char* __restrict__ st8, const int* __restrict__ st32,
                            const int* __restrict__ modep, const float* __restrict__ a,
                            const float* __restrict__ b, const float2* __restrict__ s0buf,
                            u32* __restrict__ scaled, int c0) {
  int chunk = c0 + blockIdx.x, r = blockIdx.y, c = threadIdx.x;
  int mode = modep[0];
  int t0 = chunk * CLEN;
  float rho = __expf(-fabsf(a[r]));
  float bb = b[c];
  float er = rho * __cosf(bb), ei = rho * __sinf(bb);
  float pv = pT[r * T_LEN + t0 + c];
  int sv = read_start(st8, st32, mode, t0 + c);
  float2 s0 = s0buf[((size_t)chunk * 64 + r) * 64 + c];
  float Sr = s0.x, Si = s0.y;
  int tl0 = (chunk - c0) * CLEN;
  const float* qrow = q + (size_t)t0 * 64 + c;
  u32* srow = scaled + (size_t)tl0 * 4096;
  const int Ldw = r * 64 + c;
#pragma unroll 4
  for (int i = 0; i < CLEN; ++i) {
    float qt = qrow[i * 64];
    float pt = __shfl(pv, i);
    int st = __shfl(sv, i);
    float pre = pt * qt;
    float cer = st ? 0.f : er;
    float cei = st ? 0.f : ei;
    float nSr = cer * Sr - cei * Si + pre;
    Si = cer * Si + cei * Sr;
    Sr = nSr;
    float m2 = fmaf(Sr, Sr, Si * Si);
    float rsq = rsqrtf(fmaxf(m2, 1e-30f));
    float m = m2 * rsq;
    float sc = __log2f(1.0f + m) * 0.6931471805599453f * rsq;
    u32 pack = ((u32)f2bf_bits(sc * Sr) << 16) | (u32)f2bf_bits(sc * Si);
    srow[(size_t)i * 4096 + (Ldw ^ ((i & 7) << 2))] = pack;
  }
}

// ---------------- LN + LeakyReLU over bf16 split-K partials -> z0bf (unswizzled) ----------------
__global__ void ln_act16(const u16* __restrict__ parts, int KS, size_t pstride,
                         const float* __restrict__ bias, const float* __restrict__ gam,
                         const float* __restrict__ bet, u16* __restrict__ zbf) {
  __shared__ float red[8];
  int t = blockIdx.x, tid = threadIdx.x;
  size_t o = (size_t)t * D_DIM + tid;
  float v0 = bias[tid];
  float v1 = bias[tid + 256];
  for (int ks = 0; ks < KS; ++ks) {
    v0 += bf2f(parts[(size_t)ks * pstride + o]);
    v1 += bf2f(parts[(size_t)ks * pstride + o + 256]);
  }
  float s = wave_sum(v0 + v1);
  if ((tid & 63) == 0) red[tid >> 6] = s;
  __syncthreads();
  float mean = (red[0] + red[1] + red[2] + red[3]) * (1.f / 512.f);
  float d0 = v0 - mean, d1 = v1 - mean;
  float s2 = wave_sum(d0 * d0 + d1 * d1);
  if ((tid & 63) == 0) red[4 + (tid >> 6)] = s2;
  __syncthreads();
  float var = (red[4] + red[5] + red[6] + red[7]) * (1.f / 512.f);
  float rstd = rsqrtf(var + 1e-5f);
  float z0 = d0 * rstd * gam[tid] + bet[tid];
  float z1 = d1 * rstd * gam[tid + 256] + bet[tid + 256];
  z0 = z0 > 0.f ? z0 : 0.01f * z0;
  z1 = z1 > 0.f ? z1 : 0.01f * z1;
  zbf[o] = f2bf_bits(z0);
  zbf[o + 256] = f2bf_bits(z1);
}

// ---------------- LN + LeakyReLU over fp32 y (W1 epilogue) ----------------
__global__ void ln_act32(const float* __restrict__ y, const float* __restrict__ bias,
                         const float* __restrict__ gam, const float* __restrict__ bet,
                         const float* __restrict__ xsrc, float* __restrict__ xdst,
                         u16* __restrict__ xbf_next, float* __restrict__ finout) {
  __shared__ float red[8];
  int t = blockIdx.x, tid = threadIdx.x;
  size_t o = (size_t)t * D_DIM + tid;
  float v0 = y[o] + bias[tid];
  float v1 = y[o + 256] + bias[tid + 256];
  float s = wave_sum(v0 + v1);
  if ((tid & 63) == 0) red[tid >> 6] = s;
  __syncthreads();
  float mean = (red[0] + red[1] + red[2] + red[3]) * (1.f / 512.f);
  float d0 = v0 - mean, d1 = v1 - mean;
  float s2 = wave_sum(d0 * d0 + d1 * d1);
  if ((tid & 63) == 0) red[4 + (tid >> 6)] = s2;
  __syncthreads();
  float var = (red[4] + red[5] + red[6] + red[7]) * (1.f / 512.f);
  float rstd = rsqrtf(var + 1e-5f);
  float z0 = d0 * rstd * gam[tid] + bet[tid];
  float z1 = d1 * rstd * gam[tid + 256] + bet[tid + 256];
  z0 = z0 > 0.f ? z0 : 0.01f * z0;
  z1 = z1 > 0.f ? z1 : 0.01f * z1;
  if (xdst) {
    float x0 = xsrc[o] + z0, x1 = xsrc[o + 256] + z1;
    xdst[o] = x0;
    xdst[o + 256] = x1;
    xbf_next[o] = f2bf_bits(x0);
    xbf_next[o + 256] = f2bf_bits(x1);
  }
  if (finout) {
    finout[o] = z0;
    finout[o + 256] = z1;
  }
}

__global__ void err_signal(float* __restrict__ out, float code) {
  if (threadIdx.x == 0) out[0] = code;
}

// ---------------- host launch ----------------
extern "C" void kernel_launch(void* const* d_in, const int* in_sizes, int n_in, void* d_out,
                              int out_size, void* d_ws, size_t ws_size, hipStream_t stream) {
  const float* x_in = (const float*)d_in[0];
  const float* state = (const float*)d_in[1];
  const unsigned char* start8 = (const unsigned char*)d_in[2];
  const int* start32 = (const int*)d_in[2];
  const float* Wtr = (const float*)d_in[3];
  const float* Wc = (const float*)d_in[4];
  const float* a_in = (const float*)d_in[5];
  const float* b_in = (const float*)d_in[6];
  const float* W0 = (const float*)d_in[7];
  const float* b0 = (const float*)d_in[8];
  const float* g0 = (const float*)d_in[9];
  const float* beta0 = (const float*)d_in[10];
  const float* W1 = (const float*)d_in[11];
  const float* b1 = (const float*)d_in[12];
  const float* g1 = (const float*)d_in[13];
  const float* beta1 = (const float*)d_in[14];
  float* out = (float*)d_out;

  // one-time: allow 96 KiB dynamic LDS for the 8-phase GEMM
  static int attr_state = 0;  // 0 unset, 1 ok, -1 failed
  if (attr_state == 0)
    attr_state = (hipFuncSetAttribute((const void*)gemm_8ph,
                                      hipFuncAttributeMaxDynamicSharedMemorySize,
                                      98304) == hipSuccess)
                     ? 1
                     : -1;
  const bool attr_ok = (attr_state == 1);

  char* w = (char*)d_ws;
  auto alloc = [&](size_t bytes) {
    char* ptr = w;
    w += (bytes + 255) & ~(size_t)255;
    return ptr;
  };
  float* x_ws = (float*)alloc(4ull * T_LEN * D_DIM);            // 8 MB
  u16* xbf = (u16*)alloc(2ull * T_LEN * D_DIM);                 // 4 MB
  u16* wcat = (u16*)alloc(2ull * 128 * D_DIM);                  // 128 KB
  u16* w0bf = (u16*)alloc(2ull * D_DIM * F_DIM);                // 8 MB (per-layer)
  u16* w1bf = (u16*)alloc(2ull * 3 * D_DIM * D_DIM);            // 1.5 MB (all layers)
  float* trct = (float*)alloc(4ull * T_LEN * 128);              // 2 MB
  float* pTbuf = (float*)alloc(4ull * T_LEN * 64);              // 1 MB
  float* qbuf = (float*)alloc(4ull * T_LEN * 64);               // 1 MB
  float4* chunkbuf = (float4*)alloc(16ull * NCHUNK * 64 * 64);  // 4 MB
  float2* s0buf = (float2*)alloc(8ull * NCHUNK * 64 * 64);      // 2 MB
  u16* z0bf = (u16*)alloc(2ull * T_LEN * D_DIM);                // 4 MB
  float* ybuf = (float*)alloc(4ull * T_LEN * D_DIM);            // 8 MB (W1 out)
  int* modep = (int*)alloc(256);
  size_t base1 = (size_t)(w - (char*)d_ws);

  if (n_in != 15) {
    err_signal<<<1, 64, 0, stream>>>(out, 9e6f + 1000.f * n_in);
    return;
  }
  const size_t MB = 1ull << 20;
  const size_t pstride = (size_t)T_LEN * D_DIM;  // elements per partial slab
  int KS, nseg;
  if (ws_size >= base1 + 16 * MB + 64 * MB) { KS = 4; nseg = 1; }
  else if (ws_size >= base1 + 16 * MB + 32 * MB) { KS = 4; nseg = 2; }
  else if (ws_size >= base1 + 8 * MB + 32 * MB) { KS = 2; nseg = 2; }
  else if (ws_size >= base1 + 8 * MB + 16 * MB) { KS = 2; nseg = 4; }
  else if (ws_size >= base1 + 4 * MB + 16 * MB) { KS = 1; nseg = 4; }
  else {
    err_signal<<<1, 64, 0, stream>>>(out, 9e6f);
    return;
  }
  const int seg_rows = T_LEN / nseg;
  const int seg_chunks = NCHUNK / nseg;
  u16* ypart = (u16*)alloc(2ull * KS * pstride);
  u16* scaled = (u16*)alloc(2ull * seg_rows * F_DIM);

  const bool use8 = (nseg == 1) && attr_ok;  // seg_rows==4096 -> grid.x=16

  detect_start<<<1, 256, 0, stream>>>(start8, modep);
  f2bf<<<(T_LEN * D_DIM) / 256, 256, 0, stream>>>(x_in, xbf, T_LEN * D_DIM);
  f2bf<<<(3 * D_DIM * D_DIM) / 256, 256, 0, stream>>>(W1, w1bf, 3 * D_DIM * D_DIM);

  for (int l = 0; l < 3; ++l) {
    const float* Wtr_l = Wtr + (size_t)l * 64 * D_DIM;
    const float* Wc_l = Wc + (size_t)l * 64 * D_DIM;
    const float* a_l = a_in + l * 64;
    const float* b_l = b_in + l * 64;
    const float* W0_l = W0 + (size_t)l * D_DIM * F_DIM;
    const u16* w1bf_l = w1bf + (size_t)l * D_DIM * D_DIM;
    const float* state_l = state + (size_t)l * 64 * 64;
    const float* xsrc = (l == 0) ? x_in : x_ws;

    k_conv<<<(128 * D_DIM + D_DIM * F_DIM) / 256, 256, 0, stream>>>(Wtr_l, Wc_l, wcat, W0_l,
                                                                    w0bf);
    // trct (4096 x 128) = xbf @ wcat^T
    gemm_bt<64, 64, 2, 2><<<dim3(T_LEN / 64, 2), 256, 0, stream>>>(xbf, wcat, trct, T_LEN, 128,
                                                                   D_DIM);
    prep_pq<<<T_LEN, 64, 0, stream>>>(trct, pTbuf, qbuf);
    scan_phase1<<<dim3(NCHUNK, 64), 64, 0, stream>>>(pTbuf, qbuf, start8, start32, modep, a_l,
                                                     b_l, chunkbuf);
    scan_phase2<<<64, 64, 0, stream>>>(chunkbuf, state_l, s0buf);

    for (int h = 0; h < nseg; ++h) {
      scan_phase3<<<dim3(seg_chunks, 64), 64, 0, stream>>>(pTbuf, qbuf, start8, start32, modep,
                                                           a_l, b_l, s0buf, (u32*)scaled,
                                                           h * seg_chunks);
      if (use8)
        gemm_8ph<<<dim3(seg_rows / 256, D_DIM / 128, KS), 512, 98304, stream>>>(
            scaled, w0bf, ypart + (size_t)h * seg_rows * D_DIM, pstride, D_DIM, F_DIM);
      else
        gemm128<<<dim3(seg_rows / 128, D_DIM / 128, KS), 256, 0, stream>>>(
            scaled, w0bf, ypart + (size_t)h * seg_rows * D_DIM, pstride, D_DIM, F_DIM);
    }
    ln_act16<<<T_LEN, 256, 0, stream>>>(ypart, KS, pstride, b0 + l * D_DIM, g0 + l * D_DIM,
                                        beta0 + l * D_DIM, z0bf);
    // y2 = z0 (4096x512) @ W1 (512x512)^T — no split-K, grid 64x8 = 512 blocks
    gemm_bt<64, 64, 2, 2><<<dim3(T_LEN / 64, D_DIM / 64), 256, 0, stream>>>(z0bf, w1bf_l, ybuf,
                                                                            T_LEN, D_DIM, D_DIM);
    ln_act32<<<T_LEN, 256, 0, stream>>>(ybuf, b1 + l * D_DIM, g1 + l * D_DIM, beta1 + l * D_DIM,
                                        (l < 2) ? xsrc : nullptr, (l < 2) ? x_ws : nullptr,
                                        (l < 2) ? xbf : nullptr, (l == 2) ? out : nullptr);
  }
}

// Round 3
// 494.978 us; speedup vs baseline: 1.0443x; 1.0014x over previous
//
#include <hip/hip_runtime.h>
#include <hip/hip_bf16.h>
#include <math.h>

#define T_LEN 4096
#define D_DIM 512
#define F_DIM 8192
#define NCHUNK 64
#define CLEN 64

typedef short short8 __attribute__((ext_vector_type(8)));
typedef float f32x4 __attribute__((ext_vector_type(4)));
typedef unsigned short u16;
typedef unsigned int u32;

// ---------------- helpers ----------------
__device__ inline float wave_sum(float v) {
#pragma unroll
  for (int o = 32; o; o >>= 1) v += __shfl_xor(v, o);
  return v;
}

__device__ inline u16 f2bf_bits(float v) {
  __hip_bfloat16 h = __float2bfloat16(v);
  return *(u16*)&h;
}

__device__ inline float bf2f(u16 u) {
  u32 x = ((u32)u) << 16;
  return *(float*)&x;
}

__device__ inline void gl_lds16(const void* g, void* l) {
  __builtin_amdgcn_global_load_lds((const __attribute__((address_space(1))) void*)g,
                                   (__attribute__((address_space(3))) void*)l, 16, 0, 0);
}

// start[] may arrive as 1-byte bools or int32 {0,1}.
__global__ void detect_start(const unsigned char* __restrict__ s8, int* __restrict__ mode) {
  __shared__ int found;
  if (threadIdx.x == 0) found = 0;
  __syncthreads();
  for (int i = threadIdx.x; i < 4096; i += 256)
    if ((i & 3) && s8[i]) found = 1;  // benign race, same value
  __syncthreads();
  if (threadIdx.x == 0) mode[0] = found;  // 1 = byte layout, 0 = int32 layout
}

__device__ inline int read_start(const unsigned char* s8, const int* s32, int mode, int t) {
  return mode ? (int)s8[t] : s32[t];
}

// ---------------- fp32 -> bf16(bits) convert (plain) ----------------
__global__ void f2bf(const float* __restrict__ s, u16* __restrict__ d, int n) {
  int i = blockIdx.x * 256 + threadIdx.x;
  if (i < n) d[i] = f2bf_bits(s[i]);
}

// fused per-layer weight conversion:
//   wcat = concat [Wtr_l; Wc_l] (128 x 512), unswizzled (BK=32 gemm)
//   w0bf: K-permute (f = r*128+2c+b <- b*4096+r*64+c) + granule swizzle by (d&7)
__global__ void k_conv(const float* __restrict__ wtr, const float* __restrict__ wc,
                       u16* __restrict__ wcat, const float* __restrict__ w0,
                       u16* __restrict__ w0bf) {
  int i = blockIdx.x * 256 + threadIdx.x;
  if (i < 128 * D_DIM) {
    float v = (i < 64 * D_DIM) ? wtr[i] : wc[i - 64 * D_DIM];
    wcat[i] = f2bf_bits(v);
  }
  int j = i - 128 * D_DIM;
  if (j >= 0 && j < D_DIM * F_DIM) {
    int d = j >> 13, f = j & 8191;
    int r = f >> 7, rem = f & 127;
    int c = rem >> 1, b = rem & 1;
    float v = w0[(size_t)d * 8192 + b * 4096 + r * 64 + c];
    w0bf[(size_t)d * 8192 + (f ^ ((d & 7) << 3))] = f2bf_bits(v);
  }
}

// ---------------- small MFMA GEMM (64x64 tile, BK=32, sync staging) — trct & W1 ----------------
template <int BM, int BN, int WR, int WC>
__global__ __launch_bounds__(256) void gemm_bt(const u16* __restrict__ A,
                                               const u16* __restrict__ B,
                                               float* __restrict__ C, int M, int N, int K) {
  constexpr int BK = 32;
  constexpr int MT = BM / (WR * 16);
  constexpr int NT = BN / (WC * 16);
  constexpr int AG = BM / 64;
  constexpr int BG = BN / 64;
  __shared__ u16 sA[BM * BK];
  __shared__ u16 sB[BN * BK];
  const int m0 = blockIdx.x * BM;
  const int n0 = blockIdx.y * BN;
  const int tid = threadIdx.x;
  const int wave = tid >> 6;
  const int lane = tid & 63;
  const int wr = wave / WC;
  const int wc = wave % WC;
  const int row_l = tid >> 2;
  const int c8 = (tid & 3) << 3;
  const int frow = lane & 15;
  const int fcol = (lane >> 4) << 3;

  f32x4 acc[MT][NT];
#pragma unroll
  for (int i = 0; i < MT; ++i)
#pragma unroll
    for (int j = 0; j < NT; ++j) acc[i][j] = (f32x4){0.f, 0.f, 0.f, 0.f};

  for (int k0 = 0; k0 < K; k0 += BK) {
#pragma unroll
    for (int j = 0; j < AG; ++j) {
      uint4 v = *(const uint4*)(A + (size_t)(m0 + j * 64 + row_l) * K + (k0 + c8));
      *(uint4*)(sA + (j * 64 + row_l) * BK + c8) = v;
    }
#pragma unroll
    for (int j = 0; j < BG; ++j) {
      uint4 v = *(const uint4*)(B + (size_t)(n0 + j * 64 + row_l) * K + (k0 + c8));
      *(uint4*)(sB + (j * 64 + row_l) * BK + c8) = v;
    }
    __syncthreads();
    short8 af[MT], bfr[NT];
#pragma unroll
    for (int i = 0; i < MT; ++i)
      af[i] = *(const short8*)(sA + (wr * MT * 16 + i * 16 + frow) * BK + fcol);
#pragma unroll
    for (int j = 0; j < NT; ++j)
      bfr[j] = *(const short8*)(sB + (wc * NT * 16 + j * 16 + frow) * BK + fcol);
#pragma unroll
    for (int i = 0; i < MT; ++i)
#pragma unroll
      for (int j = 0; j < NT; ++j)
        acc[i][j] = __builtin_amdgcn_mfma_f32_16x16x32_bf16(af[i], bfr[j], acc[i][j], 0, 0, 0);
    __syncthreads();
  }
#pragma unroll
  for (int i = 0; i < MT; ++i) {
    const int rbase = m0 + wr * MT * 16 + i * 16 + ((lane >> 4) << 2);
#pragma unroll
    for (int j = 0; j < NT; ++j) {
      const int col = n0 + wc * NT * 16 + j * 16 + (lane & 15);
#pragma unroll
      for (int rg = 0; rg < 4; ++rg) C[(size_t)(rbase + rg) * N + col] = acc[i][j][rg];
    }
  }
}

// ---------------- 128x128 MFMA GEMM, BK=64, XOR-swizzled operands, split-K, bf16 partials ----
// (retained for low-workspace fallback paths)
// A, B global layout: row-major with 16B granule g of each row stored at g ^ (row&7).
__global__ __launch_bounds__(256) void gemm128(const u16* __restrict__ A,
                                               const u16* __restrict__ B,
                                               u16* __restrict__ Cp, size_t pstride, int N,
                                               int Ktot) {
  __shared__ u16 sA[128 * 64];
  __shared__ u16 sB[128 * 64];
  const int tid = threadIdx.x;
  const int wave = tid >> 6;
  const int lane = tid & 63;
  const int wr = wave >> 1;
  const int wc = wave & 1;
  const int m0 = blockIdx.x * 128;
  const int n0 = blockIdx.y * 128;
  const int ks = blockIdx.z;
  const int Kper = Ktot / gridDim.z;
  const int kb = ks * Kper;
  const int row_s = tid >> 3;     // 0..31 staging row within 32-row group
  const int g8 = (tid & 7) << 3;  // granule offset (elems)
  const int frow = lane & 15;
  const int quad = lane >> 4;
  const int sw = frow & 7;

  f32x4 acc[4][4];
#pragma unroll
  for (int i = 0; i < 4; ++i)
#pragma unroll
    for (int j = 0; j < 4; ++j) acc[i][j] = (f32x4){0.f, 0.f, 0.f, 0.f};

  for (int k0 = kb; k0 < kb + Kper; k0 += 64) {
#pragma unroll
    for (int j = 0; j < 4; ++j) {
      gl_lds16(A + (size_t)(m0 + j * 32 + row_s) * Ktot + (k0 + g8), sA + j * 2048 + wave * 512);
      gl_lds16(B + (size_t)(n0 + j * 32 + row_s) * Ktot + (k0 + g8), sB + j * 2048 + wave * 512);
    }
    asm volatile("s_waitcnt vmcnt(0)" ::: "memory");
    __syncthreads();
#pragma unroll
    for (int kk = 0; kk < 2; ++kk) {
      const int gA = (((kk << 2) | quad) ^ sw) << 3;  // swizzled elem offset in row
      short8 af[4], bfr[4];
#pragma unroll
      for (int i = 0; i < 4; ++i)
        af[i] = *(const short8*)(sA + (wr * 64 + i * 16 + frow) * 64 + gA);
#pragma unroll
      for (int j = 0; j < 4; ++j)
        bfr[j] = *(const short8*)(sB + (wc * 64 + j * 16 + frow) * 64 + gA);
#pragma unroll
      for (int i = 0; i < 4; ++i)
#pragma unroll
        for (int j = 0; j < 4; ++j)
          acc[i][j] = __builtin_amdgcn_mfma_f32_16x16x32_bf16(af[i], bfr[j], acc[i][j], 0, 0, 0);
    }
    __syncthreads();
  }
#pragma unroll
  for (int i = 0; i < 4; ++i) {
    const int rbase = m0 + wr * 64 + i * 16 + ((lane >> 4) << 2);
#pragma unroll
    for (int j = 0; j < 4; ++j) {
      const int col = n0 + wc * 64 + j * 16 + (lane & 15);
#pragma unroll
      for (int rg = 0; rg < 4; ++rg)
        Cp[(size_t)ks * pstride + (size_t)(rbase + rg) * N + col] = f2bf_bits(acc[i][j][rg]);
    }
  }
}

// ---------------- 256x128 MFMA GEMM, 8-phase READ-AHEAD pipeline (T2+T3+T4+T5+T14) --------
// v3: fragment ds_reads are issued ONE PHASE AHEAD with counted lgkmcnt(4) (leave own
// reads in flight; seal the previous phase's reads, which feed this phase's MFMA). This
// overlaps the LDS-read pipe (the R2 limiter: 4x8 waves x ~12cyc = 384 cyc/phase) with
// the MFMA pipe (310 cyc/phase) instead of serializing them at a lgkmcnt(0) drain.
// Reads are balanced to exactly 4 ds_read_b128/wave/phase:
//   p0:bf1(e) p1:af_hi(e) p2:af_lo(o,+2ahead) p3:bf0B(o,+2) p4:bf1(o) p5:af_hi(o)
//   p6:af_lo(e',+2) p7:bf0A(e',+2)       (e=even tile buf0, o=odd tile buf1, '=next iter)
// Stages (issued AFTER the lgkm wait -> provably ordered behind all prior-phase reads;
// same-phase read/stage regions verified disjoint):
//   p0:B_odd  p2:A_even'{0,2}  p3:A_even'{1,3}  p4:B_even'  p6:A_odd'{0,2}  p7:A_odd'{1,3}
// vmcnt checkpoints (FIFO ledger, counted, never 0 except final-iter p2):
//   p1:vmcnt(2) seals A_odd{0,2}+{1,3} (staged prev p6/p7)   -> af_lo(o) readable at p2
//   p2:vmcnt(2) seals B_odd (p0)                             -> bf0B readable at p3
//   p5:vmcnt(2) seals A_even'{0,2}+{1,3} (p2/p3)             -> af_lo(e') readable at p6
//   p6:vmcnt(2) seals B_even' (p4)                           -> bf0A readable at p7
// Prologue leaves exactly 4 loads in flight (A_odd{0,2},{1,3}) matching steady state.
// Per-acc-element MFMA order is IDENTICAL to v2 (quadrants 00,01,11,10; kk=0,1 ascending;
// KS=4; bf16 rounding at C-write) -> bit-identical output.
__global__ __launch_bounds__(512, 2) void gemm_8ph(const u16* __restrict__ A,
                                                   const u16* __restrict__ B,
                                                   u16* __restrict__ Cp, size_t pstride, int N,
                                                   int Ktot) {
  extern __shared__ u16 smem[];
  u16* sA = smem;          // [2][256*64]
  u16* sB = smem + 32768;  // [2][128*64]
  const int tid = threadIdx.x;
  const int wave = tid >> 6;
  const int lane = tid & 63;
  const int wr = wave >> 1;  // 0..3 -> 64-row group
  const int wc = wave & 1;   // 0..1 -> 64-col group
  const int m0 = blockIdx.x * 256;
  const int n0 = blockIdx.y * 128;
  const int ks = blockIdx.z;
  const int Kper = Ktot / gridDim.z;
  const int kb = ks * Kper;
  const int NITER = Kper >> 7;  // 128 K per iteration (2 x BK=64 tiles)
  const int r_l = tid >> 3;     // row within 64-row load group
  const int g8 = (tid & 7) << 3;
  const int frow = lane & 15;
  const int quad = lane >> 4;
  const int sw = frow & 7;
  const int o0 = (quad ^ sw) << 3;        // swizzled elem offset, kk=0
  const int o1 = ((4 | quad) ^ sw) << 3;  // swizzled elem offset, kk=1

  const u16* Abase = A + (size_t)(m0 + r_l) * Ktot + g8;
  const u16* Bbase = B + (size_t)(n0 + r_l) * Ktot + g8;

#define STAGE_A(l, k0, b) \
  gl_lds16(Abase + (size_t)(l) * 64 * Ktot + (k0), sA + (b)*16384 + (l)*4096 + wave * 512)
#define STAGE_B(l, k0, b) \
  gl_lds16(Bbase + (size_t)(l) * 64 * Ktot + (k0), sB + (b)*8192 + (l)*4096 + wave * 512)
// 4x ds_read_b128: A frags (2 m-frags x kk=0,1) for row-half qm_ of this wave's 64 rows
#define RD_A(dst, b, qm_)                                                          \
  do {                                                                             \
    const u16* _p = sA + (b)*16384 + (wr * 64 + (qm_)*32 + frow) * 64;             \
    dst[0][0] = *(const short8*)(_p + o0);                                         \
    dst[0][1] = *(const short8*)(_p + o1);                                         \
    dst[1][0] = *(const short8*)(_p + 1024 + o0);                                  \
    dst[1][1] = *(const short8*)(_p + 1024 + o1);                                  \
  } while (0)
// 4x ds_read_b128: B frags (2 n-frags x kk=0,1) for col-half half_ of this wave's 64 cols
#define RD_B(dst, b, half_)                                                        \
  do {                                                                             \
    const u16* _p = sB + (b)*8192 + (wc * 64 + (half_)*32 + frow) * 64;            \
    dst[0][0] = *(const short8*)(_p + o0);                                         \
    dst[0][1] = *(const short8*)(_p + o1);                                         \
    dst[1][0] = *(const short8*)(_p + 1024 + o0);                                  \
    dst[1][1] = *(const short8*)(_p + 1024 + o1);                                  \
  } while (0)

  f32x4 acc[4][4];
#pragma unroll
  for (int i = 0; i < 4; ++i)
#pragma unroll
    for (int j = 0; j < 4; ++j) acc[i][j] = (f32x4){0.f, 0.f, 0.f, 0.f};

  short8 af_lo[2][2];  // A rows qm=0 of current tile
  short8 af_hi[2][2];  // A rows qm=1 of current tile
  short8 bf1r[2][2];   // B cols 32..63 of current tile
  short8 bf0A[2][2];   // B cols 0..31, even tiles (buf0)
  short8 bf0B[2][2];   // B cols 0..31, odd tiles (buf1)

  // Prologue: tile0 A+B (6), then tile1 A{0,2} (p6-equiv) and A{1,3} (p7-equiv).
  STAGE_A(0, kb, 0);
  STAGE_A(1, kb, 0);
  STAGE_A(2, kb, 0);
  STAGE_A(3, kb, 0);
  STAGE_B(0, kb, 0);
  STAGE_B(1, kb, 0);
  STAGE_A(0, kb + 64, 1);
  STAGE_A(2, kb + 64, 1);
  STAGE_A(1, kb + 64, 1);
  STAGE_A(3, kb + 64, 1);
  asm volatile("s_waitcnt vmcnt(4)" ::: "memory");  // seal tile0; leave tile1-A in flight
  __builtin_amdgcn_s_barrier();
  RD_A(af_lo, 0, 0);  // feeds p0 (sealed by p0's lgkmcnt(4))
  RD_B(bf0A, 0, 0);

  for (int I = 0; I < NITER; ++I) {
    const int k0e = kb + (I << 7);  // even tile k-offset
    const bool nl = (I < NITER - 1);
#pragma unroll
    for (int p = 0; p < 8; ++p) {
      // ---- read-ahead ds_reads (for phase p+1 / p+2) ----
      if (p == 0) RD_B(bf1r, 0, 1);
      if (p == 1) RD_A(af_hi, 0, 1);
      if (p == 2) RD_A(af_lo, 1, 0);
      if (p == 3) RD_B(bf0B, 1, 0);
      if (p == 4) RD_B(bf1r, 1, 1);
      if (p == 5) RD_A(af_hi, 1, 1);
      if (p == 6 && nl) RD_A(af_lo, 0, 0);
      if (p == 7 && nl) RD_B(bf0A, 0, 0);
      __builtin_amdgcn_s_barrier();
      // counted lgkm wait: seal previous phase's reads, leave own in flight
      if (p == 6 || p == 7) {
        if (nl)
          asm volatile("s_waitcnt lgkmcnt(4)" ::: "memory");
        else
          asm volatile("s_waitcnt lgkmcnt(0)" ::: "memory");
      } else {
        asm volatile("s_waitcnt lgkmcnt(4)" ::: "memory");
      }
      __builtin_amdgcn_sched_barrier(0);
      // ---- staging (after lgkm wait -> ordered behind all prior-phase reads) ----
      if (p == 0) { STAGE_B(0, k0e + 64, 1); STAGE_B(1, k0e + 64, 1); }
      if (p == 2 && nl) { STAGE_A(0, k0e + 128, 0); STAGE_A(2, k0e + 128, 0); }
      if (p == 3 && nl) { STAGE_A(1, k0e + 128, 0); STAGE_A(3, k0e + 128, 0); }
      if (p == 4 && nl) { STAGE_B(0, k0e + 128, 0); STAGE_B(1, k0e + 128, 0); }
      if (p == 6 && nl) { STAGE_A(0, k0e + 192, 1); STAGE_A(2, k0e + 192, 1); }
      if (p == 7 && nl) { STAGE_A(1, k0e + 192, 1); STAGE_A(3, k0e + 192, 1); }
      // ---- compute (operands loaded in earlier phases) ----
      __builtin_amdgcn_s_setprio(1);
#pragma unroll
      for (int f = 0; f < 2; ++f)
#pragma unroll
        for (int g = 0; g < 2; ++g)
#pragma unroll
          for (int kk = 0; kk < 2; ++kk) {
            if (p == 0)
              acc[f][g] = __builtin_amdgcn_mfma_f32_16x16x32_bf16(af_lo[f][kk], bf0A[g][kk],
                                                                  acc[f][g], 0, 0, 0);
            if (p == 1)
              acc[f][2 + g] = __builtin_amdgcn_mfma_f32_16x16x32_bf16(af_lo[f][kk], bf1r[g][kk],
                                                                      acc[f][2 + g], 0, 0, 0);
            if (p == 2)
              acc[2 + f][2 + g] = __builtin_amdgcn_mfma_f32_16x16x32_bf16(
                  af_hi[f][kk], bf1r[g][kk], acc[2 + f][2 + g], 0, 0, 0);
            if (p == 3)
              acc[2 + f][g] = __builtin_amdgcn_mfma_f32_16x16x32_bf16(af_hi[f][kk], bf0A[g][kk],
                                                                      acc[2 + f][g], 0, 0, 0);
            if (p == 4)
              acc[f][g] = __builtin_amdgcn_mfma_f32_16x16x32_bf16(af_lo[f][kk], bf0B[g][kk],
                                                                  acc[f][g], 0, 0, 0);
            if (p == 5)
              acc[f][2 + g] = __builtin_amdgcn_mfma_f32_16x16x32_bf16(af_lo[f][kk], bf1r[g][kk],
                                                                      acc[f][2 + g], 0, 0, 0);
            if (p == 6)
              acc[2 + f][2 + g] = __builtin_amdgcn_mfma_f32_16x16x32_bf16(
                  af_hi[f][kk], bf1r[g][kk], acc[2 + f][2 + g], 0, 0, 0);
            if (p == 7)
              acc[2 + f][g] = __builtin_amdgcn_mfma_f32_16x16x32_bf16(af_hi[f][kk], bf0B[g][kk],
                                                                      acc[2 + f][g], 0, 0, 0);
          }
      __builtin_amdgcn_s_setprio(0);
      // ---- counted vmcnt checkpoints (seal staged regions for upcoming reads) ----
      if (p == 1) asm volatile("s_waitcnt vmcnt(2)" ::: "memory");
      if (p == 2) {
        if (nl)
          asm volatile("s_waitcnt vmcnt(2)" ::: "memory");
        else
          asm volatile("s_waitcnt vmcnt(0)" ::: "memory");
      }
      if (p == 5 && nl) asm volatile("s_waitcnt vmcnt(2)" ::: "memory");
      if (p == 6 && nl) asm volatile("s_waitcnt vmcnt(2)" ::: "memory");
      __builtin_amdgcn_s_barrier();
    }
  }
#undef STAGE_A
#undef STAGE_B
#undef RD_A
#undef RD_B

#pragma unroll
  for (int i = 0; i < 4; ++i) {
    const int rbase = m0 + wr * 64 + i * 16 + (quad << 2);
#pragma unroll
    for (int j = 0; j < 4; ++j) {
      const int col = n0 + wc * 64 + j * 16 + frow;
#pragma unroll
      for (int rg = 0; rg < 4; ++rg)
        Cp[(size_t)ks * pstride + (size_t)(rbase + rg) * N + col] = f2bf_bits(acc[i][j][rg]);
    }
  }
}

// ---------------- p/q prep: pT=|tr| transposed, q=|ct|/(1e-8+Sp*Sq) ----------------
__global__ void prep_pq(const float* __restrict__ trct, float* __restrict__ pT,
                        float* __restrict__ q) {
  int t = blockIdx.x;
  int lane = threadIdx.x;  // 64
  float tr = trct[t * 128 + lane];
  float ct = trct[t * 128 + 64 + lane];
  float ap = fabsf(tr), aq = fabsf(ct);
  float Sp = wave_sum(ap);
  float Sq = wave_sum(aq);
  float denom = 1e-8f + Sp * Sq;
  pT[lane * T_LEN + t] = ap;  // transposed for shuffle-broadcast in scans
  q[t * 64 + lane] = aq / denom;
}

// ---------------- scan phase 1: per-chunk affine summary (A,B) ----------------
__global__ void scan_phase1(const float* __restrict__ pT, const float* __restrict__ q,
                            const unsigned char* __restrict__ st8, const int* __restrict__ st32,
                            const int* __restrict__ modep, const float* __restrict__ a,
                            const float* __restrict__ b, float4* __restrict__ chunkbuf) {
  int chunk = blockIdx.x, r = blockIdx.y, c = threadIdx.x;
  int mode = modep[0];
  int t0 = chunk * CLEN;
  float na = -fabsf(a[r]);
  float rho = __expf(na);
  float bb = b[c];
  float er = rho * __cosf(bb), ei = rho * __sinf(bb);
  float pv = pT[r * T_LEN + t0 + c];             // lane c holds p for step c
  int sv = read_start(st8, st32, mode, t0 + c);  // lane c holds start for step c
  unsigned long long bal = __ballot(sv != 0);
  float Ar, Ai;
  if (bal) {
    Ar = 0.f; Ai = 0.f;
  } else {
    float mag = __expf(64.f * na);
    float ang = 64.f * bb;
    Ar = mag * __cosf(ang);
    Ai = mag * __sinf(ang);
  }
  int L = bal ? (63 - __builtin_clzll(bal)) : 0;  // wave-uniform
  float Br = 0.f, Bi = 0.f;
  const float* qrow = q + (size_t)t0 * 64 + c;
  for (int i = L; i < CLEN; ++i) {
    float pre = __shfl(pv, i) * qrow[i * 64];
    float nBr = er * Br - ei * Bi + pre;
    Bi = er * Bi + ei * Br;
    Br = nBr;
  }
  chunkbuf[((size_t)chunk * 64 + r) * 64 + c] = make_float4(Ar, Ai, Br, Bi);
}

// ---------------- scan phase 2: sequential chunk combine ----------------
__global__ void scan_phase2(const float4* __restrict__ chunkbuf, const float* __restrict__ state,
                            float2* __restrict__ s0buf) {
  int r = blockIdx.x, c = threadIdx.x;
  float Sr = state[r * 64 + c], Si = 0.f;
  for (int k = 0; k < NCHUNK; ++k) {
    s0buf[((size_t)k * 64 + r) * 64 + c] = make_float2(Sr, Si);
    float4 ab = chunkbuf[((size_t)k * 64 + r) * 64 + c];
    float nSr = ab.x * Sr - ab.y * Si + ab.z;
    Si = ab.x * Si + ab.y * Sr + ab.w;
    Sr = nSr;
  }
}

// ---------------- scan phase 3: replay + packed log-polar features (swizzled store) ----
__global__ void scan_phase3(const float* __restrict__ pT, const float* __restrict__ q,
                            const unsigned char* __restrict__ st8, const int* __restrict__ st32,
                            const int* __restrict__ modep, const float* __restrict__ a,
                            const float* __restrict__ b, const float2* __restrict__ s0buf,
                            u32* __restrict__ scaled, int c0) {
  int chunk = c0 + blockIdx.x, r = blockIdx.y, c = threadIdx.x;
  int mode = modep[0];
  int t0 = chunk * CLEN;
  float rho = __expf(-fabsf(a[r]));
  float bb = b[c];
  float er = rho * __cosf(bb), ei = rho * __sinf(bb);
  float pv = pT[r * T_LEN + t0 + c];
  int sv = read_start(st8, st32, mode, t0 + c);
  float2 s0 = s0buf[((size_t)chunk * 64 + r) * 64 + c];
  float Sr = s0.x, Si = s0.y;
  int tl0 = (chunk - c0) * CLEN;
  const float* qrow = q + (size_t)t0 * 64 + c;
  u32* srow = scaled + (size_t)tl0 * 4096;
  const int Ldw = r * 64 + c;
#pragma unroll 4
  for (int i = 0; i < CLEN; ++i) {
    float qt = qrow[i * 64];
    float pt = __shfl(pv, i);
    int st = __shfl(sv, i);
    float pre = pt * qt;
    float cer = st ? 0.f : er;
    float cei = st ? 0.f : ei;
    float nSr = cer * Sr - cei * Si + pre;
    Si = cer * Si + cei * Sr;
    Sr = nSr;
    float m2 = fmaf(Sr, Sr, Si * Si);
    float rsq = rsqrtf(fmaxf(m2, 1e-30f));
    float m = m2 * rsq;
    float sc = __log2f(1.0f + m) * 0.6931471805599453f * rsq;
    u32 pack = ((u32)f2bf_bits(sc * Sr) << 16) | (u32)f2bf_bits(sc * Si);
    srow[(size_t)i * 4096 + (Ldw ^ ((i & 7) << 2))] = pack;
  }
}

// ---------------- LN + LeakyReLU over bf16 split-K partials -> z0bf (unswizzled) ----------------
__global__ void ln_act16(const u16* __restrict__ parts, int KS, size_t pstride,
                         const float* __restrict__ bias, const float* __restrict__ gam,
                         const float* __restrict__ bet, u16* __restrict__ zbf) {
  __shared__ float red[8];
  int t = blockIdx.x, tid = threadIdx.x;
  size_t o = (size_t)t * D_DIM + tid;
  float v0 = bias[tid];
  float v1 = bias[tid + 256];
  for (int ks = 0; ks < KS; ++ks) {
    v0 += bf2f(parts[(size_t)ks * pstride + o]);
    v1 += bf2f(parts[(size_t)ks * pstride + o + 256]);
  }
  float s = wave_sum(v0 + v1);
  if ((tid & 63) == 0) red[tid >> 6] = s;
  __syncthreads();
  float mean = (red[0] + red[1] + red[2] + red[3]) * (1.f / 512.f);
  float d0 = v0 - mean, d1 = v1 - mean;
  float s2 = wave_sum(d0 * d0 + d1 * d1);
  if ((tid & 63) == 0) red[4 + (tid >> 6)] = s2;
  __syncthreads();
  float var = (red[4] + red[5] + red[6] + red[7]) * (1.f / 512.f);
  float rstd = rsqrtf(var + 1e-5f);
  float z0 = d0 * rstd * gam[tid] + bet[tid];
  float z1 = d1 * rstd * gam[tid + 256] + bet[tid + 256];
  z0 = z0 > 0.f ? z0 : 0.01f * z0;
  z1 = z1 > 0.f ? z1 : 0.01f * z1;
  zbf[o] = f2bf_bits(z0);
  zbf[o + 256] = f2bf_bits(z1);
}

// ---------------- LN + LeakyReLU over fp32 y (W1 epilogue) ----------------
__global__ void ln_act32(const float* __restrict__ y, const float* __restrict__ bias,
                         const float* __restrict__ gam, const float* __restrict__ bet,
                         const float* __restrict__ xsrc, float* __restrict__ xdst,
                         u16* __restrict__ xbf_next, float* __restrict__ finout) {
  __shared__ float red[8];
  int t = blockIdx.x, tid = threadIdx.x;
  size_t o = (size_t)t * D_DIM + tid;
  float v0 = y[o] + bias[tid];
  float v1 = y[o + 256] + bias[tid + 256];
  float s = wave_sum(v0 + v1);
  if ((tid & 63) == 0) red[tid >> 6] = s;
  __syncthreads();
  float mean = (red[0] + red[1] + red[2] + red[3]) * (1.f / 512.f);
  float d0 = v0 - mean, d1 = v1 - mean;
  float s2 = wave_sum(d0 * d0 + d1 * d1);
  if ((tid & 63) == 0) red[4 + (tid >> 6)] = s2;
  __syncthreads();
  float var = (red[4] + red[5] + red[6] + red[7]) * (1.f / 512.f);
  float rstd = rsqrtf(var + 1e-5f);
  float z0 = d0 * rstd * gam[tid] + bet[tid];
  float z1 = d1 * rstd * gam[tid + 256] + bet[tid + 256];
  z0 = z0 > 0.f ? z0 : 0.01f * z0;
  z1 = z1 > 0.f ? z1 : 0.01f * z1;
  if (xdst) {
    float x0 = xsrc[o] + z0, x1 = xsrc[o + 256] + z1;
    xdst[o] = x0;
    xdst[o + 256] = x1;
    xbf_next[o] = f2bf_bits(x0);
    xbf_next[o + 256] = f2bf_bits(x1);
  }
  if (finout) {
    finout[o] = z0;
    finout[o + 256] = z1;
  }
}

__global__ void err_signal(float* __restrict__ out, float code) {
  if (threadIdx.x == 0) out[0] = code;
}

// ---------------- host launch ----------------
extern "C" void kernel_launch(void* const* d_in, const int* in_sizes, int n_in, void* d_out,
                              int out_size, void* d_ws, size_t ws_size, hipStream_t stream) {
  const float* x_in = (const float*)d_in[0];
  const float* state = (const float*)d_in[1];
  const unsigned char* start8 = (const unsigned char*)d_in[2];
  const int* start32 = (const int*)d_in[2];
  const float* Wtr = (const float*)d_in[3];
  const float* Wc = (const float*)d_in[4];
  const float* a_in = (const float*)d_in[5];
  const float* b_in = (const float*)d_in[6];
  const float* W0 = (const float*)d_in[7];
  const float* b0 = (const float*)d_in[8];
  const float* g0 = (const float*)d_in[9];
  const float* beta0 = (const float*)d_in[10];
  const float* W1 = (const float*)d_in[11];
  const float* b1 = (const float*)d_in[12];
  const float* g1 = (const float*)d_in[13];
  const float* beta1 = (const float*)d_in[14];
  float* out = (float*)d_out;

  // one-time: allow 96 KiB dynamic LDS for the 8-phase GEMM
  static int attr_state = 0;  // 0 unset, 1 ok, -1 failed
  if (attr_state == 0)
    attr_state = (hipFuncSetAttribute((const void*)gemm_8ph,
                                      hipFuncAttributeMaxDynamicSharedMemorySize,
                                      98304) == hipSuccess)
                     ? 1
                     : -1;
  const bool attr_ok = (attr_state == 1);

  char* w = (char*)d_ws;
  auto alloc = [&](size_t bytes) {
    char* ptr = w;
    w += (bytes + 255) & ~(size_t)255;
    return ptr;
  };
  float* x_ws = (float*)alloc(4ull * T_LEN * D_DIM);            // 8 MB
  u16* xbf = (u16*)alloc(2ull * T_LEN * D_DIM);                 // 4 MB
  u16* wcat = (u16*)alloc(2ull * 128 * D_DIM);                  // 128 KB
  u16* w0bf = (u16*)alloc(2ull * D_DIM * F_DIM);                // 8 MB (per-layer)
  u16* w1bf = (u16*)alloc(2ull * 3 * D_DIM * D_DIM);            // 1.5 MB (all layers)
  float* trct = (float*)alloc(4ull * T_LEN * 128);              // 2 MB
  float* pTbuf = (float*)alloc(4ull * T_LEN * 64);              // 1 MB
  float* qbuf = (float*)alloc(4ull * T_LEN * 64);               // 1 MB
  float4* chunkbuf = (float4*)alloc(16ull * NCHUNK * 64 * 64);  // 4 MB
  float2* s0buf = (float2*)alloc(8ull * NCHUNK * 64 * 64);      // 2 MB
  u16* z0bf = (u16*)alloc(2ull * T_LEN * D_DIM);                // 4 MB
  float* ybuf = (float*)alloc(4ull * T_LEN * D_DIM);            // 8 MB (W1 out)
  int* modep = (int*)alloc(256);
  size_t base1 = (size_t)(w - (char*)d_ws);

  if (n_in != 15) {
    err_signal<<<1, 64, 0, stream>>>(out, 9e6f + 1000.f * n_in);
    return;
  }
  const size_t MB = 1ull << 20;
  const size_t pstride = (size_t)T_LEN * D_DIM;  // elements per partial slab
  int KS, nseg;
  if (ws_size >= base1 + 16 * MB + 64 * MB) { KS = 4; nseg = 1; }
  else if (ws_size >= base1 + 16 * MB + 32 * MB) { KS = 4; nseg = 2; }
  else if (ws_size >= base1 + 8 * MB + 32 * MB) { KS = 2; nseg = 2; }
  else if (ws_size >= base1 + 8 * MB + 16 * MB) { KS = 2; nseg = 4; }
  else if (ws_size >= base1 + 4 * MB + 16 * MB) { KS = 1; nseg = 4; }
  else {
    err_signal<<<1, 64, 0, stream>>>(out, 9e6f);
    return;
  }
  const int seg_rows = T_LEN / nseg;
  const int seg_chunks = NCHUNK / nseg;
  u16* ypart = (u16*)alloc(2ull * KS * pstride);
  u16* scaled = (u16*)alloc(2ull * seg_rows * F_DIM);

  const bool use8 = (nseg == 1) && attr_ok;  // seg_rows==4096 -> grid.x=16

  detect_start<<<1, 256, 0, stream>>>(start8, modep);
  f2bf<<<(T_LEN * D_DIM) / 256, 256, 0, stream>>>(x_in, xbf, T_LEN * D_DIM);
  f2bf<<<(3 * D_DIM * D_DIM) / 256, 256, 0, stream>>>(W1, w1bf, 3 * D_DIM * D_DIM);

  for (int l = 0; l < 3; ++l) {
    const float* Wtr_l = Wtr + (size_t)l * 64 * D_DIM;
    const float* Wc_l = Wc + (size_t)l * 64 * D_DIM;
    const float* a_l = a_in + l * 64;
    const float* b_l = b_in + l * 64;
    const float* W0_l = W0 + (size_t)l * D_DIM * F_DIM;
    const u16* w1bf_l = w1bf + (size_t)l * D_DIM * D_DIM;
    const float* state_l = state + (size_t)l * 64 * 64;
    const float* xsrc = (l == 0) ? x_in : x_ws;

    k_conv<<<(128 * D_DIM + D_DIM * F_DIM) / 256, 256, 0, stream>>>(Wtr_l, Wc_l, wcat, W0_l,
                                                                    w0bf);
    // trct (4096 x 128) = xbf @ wcat^T
    gemm_bt<64, 64, 2, 2><<<dim3(T_LEN / 64, 2), 256, 0, stream>>>(xbf, wcat, trct, T_LEN, 128,
                                                                   D_DIM);
    prep_pq<<<T_LEN, 64, 0, stream>>>(trct, pTbuf, qbuf);
    scan_phase1<<<dim3(NCHUNK, 64), 64, 0, stream>>>(pTbuf, qbuf, start8, start32, modep, a_l,
                                                     b_l, chunkbuf);
    scan_phase2<<<64, 64, 0, stream>>>(chunkbuf, state_l, s0buf);

    for (int h = 0; h < nseg; ++h) {
      scan_phase3<<<dim3(seg_chunks, 64), 64, 0, stream>>>(pTbuf, qbuf, start8, start32, modep,
                                                           a_l, b_l, s0buf, (u32*)scaled,
                                                           h * seg_chunks);
      if (use8)
        gemm_8ph<<<dim3(seg_rows / 256, D_DIM / 128, KS), 512, 98304, stream>>>(
            scaled, w0bf, ypart + (size_t)h * seg_rows * D_DIM, pstride, D_DIM, F_DIM);
      else
        gemm128<<<dim3(seg_rows / 128, D_DIM / 128, KS), 256, 0, stream>>>(
            scaled, w0bf, ypart + (size_t)h * seg_rows * D_DIM, pstride, D_DIM, F_DIM);
    }
    ln_act16<<<T_LEN, 256, 0, stream>>>(ypart, KS, pstride, b0 + l * D_DIM, g0 + l * D_DIM,
                                        beta0 + l * D_DIM, z0bf);
    // y2 = z0 (4096x512) @ W1 (512x512)^T — no split-K, grid 64x8 = 512 blocks
    gemm_bt<64, 64, 2, 2><<<dim3(T_LEN / 64, D_DIM / 64), 256, 0, stream>>>(z0bf, w1bf_l, ybuf,
                                                                            T_LEN, D_DIM, D_DIM);
    ln_act32<<<T_LEN, 256, 0, stream>>>(ybuf, b1 + l * D_DIM, g1 + l * D_DIM, beta1 + l * D_DIM,
                                        (l < 2) ? xsrc : nullptr, (l < 2) ? x_ws : nullptr,
                                        (l < 2) ? xbf : nullptr, (l == 2) ? out : nullptr);
  }
}